// Round 1
// baseline (3887.294 us; speedup 1.0000x reference)
//
#include <hip/hip_runtime.h>
#include <cstddef>

// Problem constants
constexpr int Bb  = 4;
constexpr int Nn  = 2048;
constexpr int Cc  = 256;
constexpr int Hh  = 128;
constexpr int NHh = 8;
constexpr int DHh = 16;
constexpr int MTOK = Bb * Nn;           // 8192 tokens

// ---------------------------------------------------------------------------
// Generic tiled GEMM: Y[M,N] = act(X[M,K] @ W[N,K]^T + bias[N])
// 64x64 tile, BK=16, 256 threads, 4x4 per thread. M,N multiples of 64; K of 16.
// ---------------------------------------------------------------------------
__global__ __launch_bounds__(256) void gemm_kernel(
    const float* __restrict__ X, const float* __restrict__ W,
    const float* __restrict__ bias, float* __restrict__ Y,
    int M, int N, int K, int relu)
{
    __shared__ float Xs[16][68];   // [k][m], pad keeps rows 16B-aligned
    __shared__ float Ws[16][68];   // [k][n]

    const int tid = threadIdx.x;
    const int tx  = tid & 15;      // n-dir (16)
    const int ty  = tid >> 4;      // m-dir (16)
    const int m0  = blockIdx.y * 64;
    const int n0  = blockIdx.x * 64;

    // staging indices: each thread loads one float4 per tile per matrix
    const int lr = tid >> 2;         // row in tile 0..63
    const int lc = (tid & 3) * 4;    // col in tile {0,4,8,12}

    float acc[4][4] = {};

    for (int k0 = 0; k0 < K; k0 += 16) {
        float4 xv = *(const float4*)(X + (size_t)(m0 + lr) * K + k0 + lc);
        float4 wv = *(const float4*)(W + (size_t)(n0 + lr) * K + k0 + lc);
        Xs[lc + 0][lr] = xv.x; Xs[lc + 1][lr] = xv.y;
        Xs[lc + 2][lr] = xv.z; Xs[lc + 3][lr] = xv.w;
        Ws[lc + 0][lr] = wv.x; Ws[lc + 1][lr] = wv.y;
        Ws[lc + 2][lr] = wv.z; Ws[lc + 3][lr] = wv.w;
        __syncthreads();

        #pragma unroll
        for (int k = 0; k < 16; ++k) {
            float4 a = *(const float4*)&Xs[k][ty * 4];
            float4 b = *(const float4*)&Ws[k][tx * 4];
            float ar[4] = {a.x, a.y, a.z, a.w};
            float br[4] = {b.x, b.y, b.z, b.w};
            #pragma unroll
            for (int i = 0; i < 4; ++i)
                #pragma unroll
                for (int j = 0; j < 4; ++j)
                    acc[i][j] += ar[i] * br[j];
        }
        __syncthreads();
    }

    #pragma unroll
    for (int i = 0; i < 4; ++i) {
        const int gm = m0 + ty * 4 + i;
        #pragma unroll
        for (int j = 0; j < 4; ++j) {
            const int gn = n0 + tx * 4 + j;
            float v = acc[i][j] + bias[gn];
            if (relu) v = fmaxf(v, 0.f);
            Y[(size_t)gm * N + gn] = v;
        }
    }
}

// ---------------------------------------------------------------------------
// Attention: one wave per query. qkv row layout [token][384] = q|k|v.
// Each lane owns 32 keys (j = c*64 + lane). Two passes (scores kept in regs).
// ---------------------------------------------------------------------------
__global__ __launch_bounds__(256) void attn_kernel(
    const float* __restrict__ qkv, float* __restrict__ out)
{
    const int lane = threadIdx.x & 63;
    const int wv   = threadIdx.x >> 6;
    const int q    = blockIdx.x * 4 + wv;
    const int hd   = blockIdx.y;
    const int b    = blockIdx.z;

    const float* base = qkv + (size_t)b * Nn * 384;
    const float* qp = base + (size_t)q * 384 + hd * DHh;

    float qv[16];
    #pragma unroll
    for (int i = 0; i < 4; ++i) {
        float4 t = ((const float4*)qp)[i];
        qv[4*i+0] = t.x; qv[4*i+1] = t.y; qv[4*i+2] = t.z; qv[4*i+3] = t.w;
    }

    // pass 1: scores for this lane's 32 keys
    float s[32];
    float m = -1e30f;
    #pragma unroll 4
    for (int c = 0; c < 32; ++c) {
        const float* kp = base + (size_t)(c * 64 + lane) * 384 + Hh + hd * DHh;
        float acc = 0.f;
        #pragma unroll
        for (int i = 0; i < 4; ++i) {
            float4 t = ((const float4*)kp)[i];
            acc += qv[4*i+0]*t.x + qv[4*i+1]*t.y + qv[4*i+2]*t.z + qv[4*i+3]*t.w;
        }
        acc *= 0.25f;              // 1/sqrt(16)
        s[c] = acc;
        m = fmaxf(m, acc);
    }
    #pragma unroll
    for (int off = 32; off > 0; off >>= 1) m = fmaxf(m, __shfl_xor(m, off));

    float l = 0.f;
    #pragma unroll
    for (int c = 0; c < 32; ++c) { s[c] = __expf(s[c] - m); l += s[c]; }
    #pragma unroll
    for (int off = 32; off > 0; off >>= 1) l += __shfl_xor(l, off);
    const float inv = 1.f / l;

    // pass 2: O = sum p_j * v_j
    float o[16];
    #pragma unroll
    for (int i = 0; i < 16; ++i) o[i] = 0.f;
    #pragma unroll 4
    for (int c = 0; c < 32; ++c) {
        const float* vp = base + (size_t)(c * 64 + lane) * 384 + 2 * Hh + hd * DHh;
        const float p = s[c];
        #pragma unroll
        for (int i = 0; i < 4; ++i) {
            float4 t = ((const float4*)vp)[i];
            o[4*i+0] += p * t.x; o[4*i+1] += p * t.y;
            o[4*i+2] += p * t.z; o[4*i+3] += p * t.w;
        }
    }
    #pragma unroll
    for (int i = 0; i < 16; ++i) {
        #pragma unroll
        for (int off = 32; off > 0; off >>= 1) o[i] += __shfl_xor(o[i], off);
    }

    if (lane == 0) {
        float* op = out + (size_t)(b * Nn + q) * Hh + hd * DHh;
        #pragma unroll
        for (int i = 0; i < 4; ++i) {
            float4 t = { o[4*i+0]*inv, o[4*i+1]*inv, o[4*i+2]*inv, o[4*i+3]*inv };
            ((float4*)op)[i] = t;
        }
    }
}

// ---------------------------------------------------------------------------
// h = LayerNorm(h + y) * g + b   — one wave per token (H=128 -> 2 elems/lane)
// ---------------------------------------------------------------------------
__global__ __launch_bounds__(256) void ln_residual_kernel(
    float* __restrict__ h, const float* __restrict__ y,
    const float* __restrict__ g, const float* __restrict__ be)
{
    const int lane = threadIdx.x & 63;
    const int wv   = threadIdx.x >> 6;
    const size_t t = (size_t)blockIdx.x * 4 + wv;

    float2 hv = ((const float2*)(h + t * Hh))[lane];
    float2 yv = ((const float2*)(y + t * Hh))[lane];
    float a0 = hv.x + yv.x, a1 = hv.y + yv.y;

    float sum = a0 + a1;
    #pragma unroll
    for (int off = 32; off > 0; off >>= 1) sum += __shfl_xor(sum, off);
    const float mean = sum * (1.f / 128.f);

    const float d0 = a0 - mean, d1 = a1 - mean;
    float vs = d0 * d0 + d1 * d1;
    #pragma unroll
    for (int off = 32; off > 0; off >>= 1) vs += __shfl_xor(vs, off);
    const float rstd = rsqrtf(vs * (1.f / 128.f) + 1e-5f);

    float2 gv = ((const float2*)g)[lane];
    float2 bv = ((const float2*)be)[lane];
    float2 r = { d0 * rstd * gv.x + bv.x, d1 * rstd * gv.y + bv.y };
    ((float2*)(h + t * Hh))[lane] = r;
}

// ---------------------------------------------------------------------------
// Final heads: logits[t][3] and head_prob[t] from o1[t][128], d1[t][64]
// ---------------------------------------------------------------------------
__global__ __launch_bounds__(256) void head_kernel(
    const float* __restrict__ o1, const float* __restrict__ d1,
    const float* __restrict__ w2, const float* __restrict__ b2,
    const float* __restrict__ dw2, const float* __restrict__ db2,
    float* __restrict__ out)
{
    const int t = blockIdx.x * blockDim.x + threadIdx.x;   // 0..8191
    const float* op = o1 + (size_t)t * 128;
    float l0 = b2[0], l1 = b2[1], l2 = b2[2];
    #pragma unroll 4
    for (int i = 0; i < 128; i += 4) {
        float4 x = *(const float4*)(op + i);
        float4 a = *(const float4*)(w2 + i);
        float4 b = *(const float4*)(w2 + 128 + i);
        float4 c = *(const float4*)(w2 + 256 + i);
        l0 += x.x*a.x + x.y*a.y + x.z*a.z + x.w*a.w;
        l1 += x.x*b.x + x.y*b.y + x.z*b.z + x.w*b.w;
        l2 += x.x*c.x + x.y*c.y + x.z*c.z + x.w*c.w;
    }
    out[(size_t)t * 3 + 0] = l0;
    out[(size_t)t * 3 + 1] = l1;
    out[(size_t)t * 3 + 2] = l2;

    const float* dp = d1 + (size_t)t * 64;
    float s = db2[0];
    #pragma unroll 4
    for (int i = 0; i < 64; i += 4) {
        float4 x = *(const float4*)(dp + i);
        float4 w = *(const float4*)(dw2 + i);
        s += x.x*w.x + x.y*w.y + x.z*w.z + x.w*w.w;
    }
    out[24576 + t] = 1.f / (1.f + __expf(-s));
}

// quality[b] = mean over N of head_prob
__global__ __launch_bounds__(256) void quality_kernel(
    const float* __restrict__ prob, float* __restrict__ q)
{
    const int b = blockIdx.x;
    const int tid = threadIdx.x;
    float s = 0.f;
    for (int i = tid; i < Nn; i += 256) s += prob[(size_t)b * Nn + i];
    #pragma unroll
    for (int off = 32; off > 0; off >>= 1) s += __shfl_xor(s, off);
    __shared__ float red[4];
    if ((tid & 63) == 0) red[tid >> 6] = s;
    __syncthreads();
    if (tid == 0) q[b] = (red[0] + red[1] + red[2] + red[3]) * (1.f / (float)Nn);
}

// ---------------------------------------------------------------------------
extern "C" void kernel_launch(void* const* d_in, const int* in_sizes, int n_in,
                              void* d_out, int out_size, void* d_ws, size_t ws_size,
                              hipStream_t stream)
{
    const float* x       = (const float*)d_in[0];
    const float* fuse_w1 = (const float*)d_in[1];
    const float* fuse_b1 = (const float*)d_in[2];
    const float* fuse_w2 = (const float*)d_in[3];
    const float* fuse_b2 = (const float*)d_in[4];

    float* ws   = (float*)d_ws;
    float* h    = ws;                                  // [8192,128]
    float* bufA = ws + (size_t)MTOK * Hh;              // up to [8192,384]
    float* bufB = bufA + (size_t)MTOK * 384;           // up to [8192,256]
    float* out  = (float*)d_out;

    const dim3 blk(256);
    auto gemm = [&](const float* X, const float* W, const float* bias, float* Y,
                    int M, int N, int K, int relu) {
        dim3 grid(N / 64, M / 64);
        hipLaunchKernelGGL(gemm_kernel, grid, blk, 0, stream, X, W, bias, Y, M, N, K, relu);
    };

    // feature fusion
    gemm(x,    fuse_w1, fuse_b1, bufB, MTOK, Hh, Cc, 1);
    gemm(bufB, fuse_w2, fuse_b2, h,    MTOK, Hh, Hh, 0);

    for (int l = 0; l < 2; ++l) {
        const int base = 5 + l * 12;
        const float* in_w  = (const float*)d_in[base + 0];
        const float* in_b  = (const float*)d_in[base + 1];
        const float* out_w = (const float*)d_in[base + 2];
        const float* out_b = (const float*)d_in[base + 3];
        const float* f1w   = (const float*)d_in[base + 4];
        const float* f1b   = (const float*)d_in[base + 5];
        const float* f2w   = (const float*)d_in[base + 6];
        const float* f2b   = (const float*)d_in[base + 7];
        const float* g1    = (const float*)d_in[base + 8];
        const float* be1   = (const float*)d_in[base + 9];
        const float* g2    = (const float*)d_in[base + 10];
        const float* be2   = (const float*)d_in[base + 11];

        gemm(h, in_w, in_b, bufA, MTOK, 3 * Hh, Hh, 0);               // qkv
        hipLaunchKernelGGL(attn_kernel, dim3(Nn / 4, NHh, Bb), blk, 0, stream, bufA, bufB);
        gemm(bufB, out_w, out_b, bufA, MTOK, Hh, Hh, 0);              // out proj
        hipLaunchKernelGGL(ln_residual_kernel, dim3(MTOK / 4), blk, 0, stream, h, bufA, g1, be1);
        gemm(h,    f1w, f1b, bufA, MTOK, 2 * Hh, Hh, 1);              // ffn up + relu
        gemm(bufA, f2w, f2b, bufB, MTOK, Hh, 2 * Hh, 0);              // ffn down
        hipLaunchKernelGGL(ln_residual_kernel, dim3(MTOK / 4), blk, 0, stream, h, bufB, g2, be2);
    }

    const float* out_w1 = (const float*)d_in[29];
    const float* out_b1 = (const float*)d_in[30];
    const float* out_w2 = (const float*)d_in[31];
    const float* out_b2 = (const float*)d_in[32];
    const float* det_w1 = (const float*)d_in[33];
    const float* det_b1 = (const float*)d_in[34];
    const float* det_w2 = (const float*)d_in[35];
    const float* det_b2 = (const float*)d_in[36];

    gemm(h, out_w1, out_b1, bufA, MTOK, Hh, Hh, 1);       // o1 [8192,128]
    gemm(h, det_w1, det_b1, bufB, MTOK, 64, Hh, 1);       // d1 [8192,64]
    hipLaunchKernelGGL(head_kernel, dim3(MTOK / 256), blk, 0, stream,
                       bufA, bufB, out_w2, out_b2, det_w2, det_b2, out);
    hipLaunchKernelGGL(quality_kernel, dim3(Bb), blk, 0, stream, out + 24576, out + 32768);
}

// Round 2
// 1327.339 us; speedup vs baseline: 2.9286x; 2.9286x over previous
//
#include <hip/hip_runtime.h>
#include <cstddef>

// Problem constants
constexpr int Bb  = 4;
constexpr int Nn  = 2048;
constexpr int Cc  = 256;
constexpr int Hh  = 128;
constexpr int NHh = 8;
constexpr int DHh = 16;
constexpr int MTOK = Bb * Nn;           // 8192 tokens

// ---------------------------------------------------------------------------
// Generic tiled GEMM: Y[M,N] = act(X[M,K] @ W[N,K]^T + bias[N])
// 64x64 tile, BK=16, 256 threads, 4x4 per thread. M,N multiples of 64; K of 16.
// ---------------------------------------------------------------------------
__global__ __launch_bounds__(256) void gemm_kernel(
    const float* __restrict__ X, const float* __restrict__ W,
    const float* __restrict__ bias, float* __restrict__ Y,
    int M, int N, int K, int relu)
{
    __shared__ float Xs[16][68];   // [k][m], pad keeps rows 16B-aligned
    __shared__ float Ws[16][68];   // [k][n]

    const int tid = threadIdx.x;
    const int tx  = tid & 15;      // n-dir (16)
    const int ty  = tid >> 4;      // m-dir (16)
    const int m0  = blockIdx.y * 64;
    const int n0  = blockIdx.x * 64;

    // staging indices: each thread loads one float4 per tile per matrix
    const int lr = tid >> 2;         // row in tile 0..63
    const int lc = (tid & 3) * 4;    // col in tile {0,4,8,12}

    float acc[4][4] = {};

    for (int k0 = 0; k0 < K; k0 += 16) {
        float4 xv = *(const float4*)(X + (size_t)(m0 + lr) * K + k0 + lc);
        float4 wv = *(const float4*)(W + (size_t)(n0 + lr) * K + k0 + lc);
        Xs[lc + 0][lr] = xv.x; Xs[lc + 1][lr] = xv.y;
        Xs[lc + 2][lr] = xv.z; Xs[lc + 3][lr] = xv.w;
        Ws[lc + 0][lr] = wv.x; Ws[lc + 1][lr] = wv.y;
        Ws[lc + 2][lr] = wv.z; Ws[lc + 3][lr] = wv.w;
        __syncthreads();

        #pragma unroll
        for (int k = 0; k < 16; ++k) {
            float4 a = *(const float4*)&Xs[k][ty * 4];
            float4 b = *(const float4*)&Ws[k][tx * 4];
            float ar[4] = {a.x, a.y, a.z, a.w};
            float br[4] = {b.x, b.y, b.z, b.w};
            #pragma unroll
            for (int i = 0; i < 4; ++i)
                #pragma unroll
                for (int j = 0; j < 4; ++j)
                    acc[i][j] += ar[i] * br[j];
        }
        __syncthreads();
    }

    #pragma unroll
    for (int i = 0; i < 4; ++i) {
        const int gm = m0 + ty * 4 + i;
        #pragma unroll
        for (int j = 0; j < 4; ++j) {
            const int gn = n0 + tx * 4 + j;
            float v = acc[i][j] + bias[gn];
            if (relu) v = fmaxf(v, 0.f);
            Y[(size_t)gm * N + gn] = v;
        }
    }
}

// ---------------------------------------------------------------------------
// Flash-style attention. One thread per query; 128 queries per block for one
// (b, head). K/V staged in LDS in 64-key tiles shared by all 128 queries.
// All lanes read the same LDS address per key -> broadcast, conflict-free.
// Online softmax with 16-key sub-tiles (scores in 16 registers).
// ---------------------------------------------------------------------------
constexpr int QT = 128;   // queries per block
constexpr int KT = 64;    // keys per LDS tile

__global__ __launch_bounds__(128) void attn_kernel(
    const float* __restrict__ qkv, float* __restrict__ out)
{
    __shared__ float Ks[KT][DHh];
    __shared__ float Vs[KT][DHh];

    const int tid = threadIdx.x;
    const int q   = blockIdx.x * QT + tid;
    const int hd  = blockIdx.y;
    const int b   = blockIdx.z;

    const float* base = qkv + (size_t)b * Nn * 384;
    const float* qp   = base + (size_t)q * 384 + hd * DHh;

    float qv[16];
    #pragma unroll
    for (int i = 0; i < 4; ++i) {
        float4 t = ((const float4*)qp)[i];
        qv[4*i+0] = t.x; qv[4*i+1] = t.y; qv[4*i+2] = t.z; qv[4*i+3] = t.w;
    }

    float m = -1e30f, l = 0.f;
    float o[16];
    #pragma unroll
    for (int i = 0; i < 16; ++i) o[i] = 0.f;

    for (int kt = 0; kt < Nn; kt += KT) {
        __syncthreads();   // all readers of previous tile done
        #pragma unroll
        for (int i = 0; i < 2; ++i) {
            const int idx = tid + i * 128;          // 0..255
            const int r = idx >> 2, c = (idx & 3) * 4;
            const float* kp = base + (size_t)(kt + r) * 384 + Hh + hd * DHh + c;
            *(float4*)&Ks[r][c] = *(const float4*)kp;
            *(float4*)&Vs[r][c] = *(const float4*)(kp + Hh);
        }
        __syncthreads();

        #pragma unroll
        for (int sub = 0; sub < KT; sub += 16) {
            float s[16];
            #pragma unroll
            for (int j = 0; j < 16; ++j) {
                const float* kr = &Ks[sub + j][0];
                float acc = 0.f;
                #pragma unroll
                for (int i = 0; i < 4; ++i) {
                    float4 t = ((const float4*)kr)[i];
                    acc += qv[4*i+0]*t.x + qv[4*i+1]*t.y
                         + qv[4*i+2]*t.z + qv[4*i+3]*t.w;
                }
                s[j] = acc * 0.25f;                 // 1/sqrt(16)
            }
            float tmax = s[0];
            #pragma unroll
            for (int j = 1; j < 16; ++j) tmax = fmaxf(tmax, s[j]);
            const float mn    = fmaxf(m, tmax);
            const float scale = __expf(m - mn);
            m = mn;
            l *= scale;
            #pragma unroll
            for (int i = 0; i < 16; ++i) o[i] *= scale;
            #pragma unroll
            for (int j = 0; j < 16; ++j) {
                const float p = __expf(s[j] - mn);
                l += p;
                const float* vr = &Vs[sub + j][0];
                #pragma unroll
                for (int i = 0; i < 4; ++i) {
                    float4 t = ((const float4*)vr)[i];
                    o[4*i+0] += p * t.x; o[4*i+1] += p * t.y;
                    o[4*i+2] += p * t.z; o[4*i+3] += p * t.w;
                }
            }
        }
    }

    const float inv = 1.f / l;
    float* op = out + (size_t)(b * Nn + q) * Hh + hd * DHh;
    #pragma unroll
    for (int i = 0; i < 4; ++i) {
        float4 t = { o[4*i+0]*inv, o[4*i+1]*inv, o[4*i+2]*inv, o[4*i+3]*inv };
        ((float4*)op)[i] = t;
    }
}

// ---------------------------------------------------------------------------
// h = LayerNorm(h + y) * g + b   — one wave per token (H=128 -> 2 elems/lane)
// ---------------------------------------------------------------------------
__global__ __launch_bounds__(256) void ln_residual_kernel(
    float* __restrict__ h, const float* __restrict__ y,
    const float* __restrict__ g, const float* __restrict__ be)
{
    const int lane = threadIdx.x & 63;
    const int wv   = threadIdx.x >> 6;
    const size_t t = (size_t)blockIdx.x * 4 + wv;

    float2 hv = ((const float2*)(h + t * Hh))[lane];
    float2 yv = ((const float2*)(y + t * Hh))[lane];
    float a0 = hv.x + yv.x, a1 = hv.y + yv.y;

    float sum = a0 + a1;
    #pragma unroll
    for (int off = 32; off > 0; off >>= 1) sum += __shfl_xor(sum, off);
    const float mean = sum * (1.f / 128.f);

    const float d0 = a0 - mean, d1 = a1 - mean;
    float vs = d0 * d0 + d1 * d1;
    #pragma unroll
    for (int off = 32; off > 0; off >>= 1) vs += __shfl_xor(vs, off);
    const float rstd = rsqrtf(vs * (1.f / 128.f) + 1e-5f);

    float2 gv = ((const float2*)g)[lane];
    float2 bv = ((const float2*)be)[lane];
    float2 r = { d0 * rstd * gv.x + bv.x, d1 * rstd * gv.y + bv.y };
    ((float2*)(h + t * Hh))[lane] = r;
}

// ---------------------------------------------------------------------------
// Final heads: logits[t][3] and head_prob[t] from o1[t][128], d1[t][64]
// ---------------------------------------------------------------------------
__global__ __launch_bounds__(256) void head_kernel(
    const float* __restrict__ o1, const float* __restrict__ d1,
    const float* __restrict__ w2, const float* __restrict__ b2,
    const float* __restrict__ dw2, const float* __restrict__ db2,
    float* __restrict__ out)
{
    const int t = blockIdx.x * blockDim.x + threadIdx.x;   // 0..8191
    const float* op = o1 + (size_t)t * 128;
    float l0 = b2[0], l1 = b2[1], l2 = b2[2];
    #pragma unroll 4
    for (int i = 0; i < 128; i += 4) {
        float4 x = *(const float4*)(op + i);
        float4 a = *(const float4*)(w2 + i);
        float4 b = *(const float4*)(w2 + 128 + i);
        float4 c = *(const float4*)(w2 + 256 + i);
        l0 += x.x*a.x + x.y*a.y + x.z*a.z + x.w*a.w;
        l1 += x.x*b.x + x.y*b.y + x.z*b.z + x.w*b.w;
        l2 += x.x*c.x + x.y*c.y + x.z*c.z + x.w*c.w;
    }
    out[(size_t)t * 3 + 0] = l0;
    out[(size_t)t * 3 + 1] = l1;
    out[(size_t)t * 3 + 2] = l2;

    const float* dp = d1 + (size_t)t * 64;
    float s = db2[0];
    #pragma unroll 4
    for (int i = 0; i < 64; i += 4) {
        float4 x = *(const float4*)(dp + i);
        float4 w = *(const float4*)(dw2 + i);
        s += x.x*w.x + x.y*w.y + x.z*w.z + x.w*w.w;
    }
    out[24576 + t] = 1.f / (1.f + __expf(-s));
}

// quality[b] = mean over N of head_prob
__global__ __launch_bounds__(256) void quality_kernel(
    const float* __restrict__ prob, float* __restrict__ q)
{
    const int b = blockIdx.x;
    const int tid = threadIdx.x;
    float s = 0.f;
    for (int i = tid; i < Nn; i += 256) s += prob[(size_t)b * Nn + i];
    #pragma unroll
    for (int off = 32; off > 0; off >>= 1) s += __shfl_xor(s, off);
    __shared__ float red[4];
    if ((tid & 63) == 0) red[tid >> 6] = s;
    __syncthreads();
    if (tid == 0) q[b] = (red[0] + red[1] + red[2] + red[3]) * (1.f / (float)Nn);
}

// ---------------------------------------------------------------------------
extern "C" void kernel_launch(void* const* d_in, const int* in_sizes, int n_in,
                              void* d_out, int out_size, void* d_ws, size_t ws_size,
                              hipStream_t stream)
{
    const float* x       = (const float*)d_in[0];
    const float* fuse_w1 = (const float*)d_in[1];
    const float* fuse_b1 = (const float*)d_in[2];
    const float* fuse_w2 = (const float*)d_in[3];
    const float* fuse_b2 = (const float*)d_in[4];

    float* ws   = (float*)d_ws;
    float* h    = ws;                                  // [8192,128]
    float* bufA = ws + (size_t)MTOK * Hh;              // up to [8192,384]
    float* bufB = bufA + (size_t)MTOK * 384;           // up to [8192,256]
    float* out  = (float*)d_out;

    const dim3 blk(256);
    auto gemm = [&](const float* X, const float* W, const float* bias, float* Y,
                    int M, int N, int K, int relu) {
        dim3 grid(N / 64, M / 64);
        hipLaunchKernelGGL(gemm_kernel, grid, blk, 0, stream, X, W, bias, Y, M, N, K, relu);
    };

    // feature fusion
    gemm(x,    fuse_w1, fuse_b1, bufB, MTOK, Hh, Cc, 1);
    gemm(bufB, fuse_w2, fuse_b2, h,    MTOK, Hh, Hh, 0);

    for (int l = 0; l < 2; ++l) {
        const int base = 5 + l * 12;
        const float* in_w  = (const float*)d_in[base + 0];
        const float* in_b  = (const float*)d_in[base + 1];
        const float* out_w = (const float*)d_in[base + 2];
        const float* out_b = (const float*)d_in[base + 3];
        const float* f1w   = (const float*)d_in[base + 4];
        const float* f1b   = (const float*)d_in[base + 5];
        const float* f2w   = (const float*)d_in[base + 6];
        const float* f2b   = (const float*)d_in[base + 7];
        const float* g1    = (const float*)d_in[base + 8];
        const float* be1   = (const float*)d_in[base + 9];
        const float* g2    = (const float*)d_in[base + 10];
        const float* be2   = (const float*)d_in[base + 11];

        gemm(h, in_w, in_b, bufA, MTOK, 3 * Hh, Hh, 0);               // qkv
        hipLaunchKernelGGL(attn_kernel, dim3(Nn / QT, NHh, Bb), dim3(QT), 0, stream, bufA, bufB);
        gemm(bufB, out_w, out_b, bufA, MTOK, Hh, Hh, 0);              // out proj
        hipLaunchKernelGGL(ln_residual_kernel, dim3(MTOK / 4), blk, 0, stream, h, bufA, g1, be1);
        gemm(h,    f1w, f1b, bufA, MTOK, 2 * Hh, Hh, 1);              // ffn up + relu
        gemm(bufA, f2w, f2b, bufB, MTOK, Hh, 2 * Hh, 0);              // ffn down
        hipLaunchKernelGGL(ln_residual_kernel, dim3(MTOK / 4), blk, 0, stream, h, bufB, g2, be2);
    }

    const float* out_w1 = (const float*)d_in[29];
    const float* out_b1 = (const float*)d_in[30];
    const float* out_w2 = (const float*)d_in[31];
    const float* out_b2 = (const float*)d_in[32];
    const float* det_w1 = (const float*)d_in[33];
    const float* det_b1 = (const float*)d_in[34];
    const float* det_w2 = (const float*)d_in[35];
    const float* det_b2 = (const float*)d_in[36];

    gemm(h, out_w1, out_b1, bufA, MTOK, Hh, Hh, 1);       // o1 [8192,128]
    gemm(h, det_w1, det_b1, bufB, MTOK, 64, Hh, 1);       // d1 [8192,64]
    hipLaunchKernelGGL(head_kernel, dim3(MTOK / 256), blk, 0, stream,
                       bufA, bufB, out_w2, out_b2, det_w2, det_b2, out);
    hipLaunchKernelGGL(quality_kernel, dim3(Bb), blk, 0, stream, out + 24576, out + 32768);
}

// Round 3
// 482.375 us; speedup vs baseline: 8.0586x; 2.7517x over previous
//
#include <hip/hip_runtime.h>
#include <cstddef>

// Problem constants
constexpr int Bb  = 4;
constexpr int Nn  = 2048;
constexpr int Cc  = 256;
constexpr int Hh  = 128;
constexpr int NHh = 8;
constexpr int DHh = 16;
constexpr int MTOK = Bb * Nn;           // 8192 tokens

typedef __attribute__((ext_vector_type(8))) short bf16x8;
typedef __attribute__((ext_vector_type(4))) short bf16x4;
typedef __attribute__((ext_vector_type(4))) float f32x4;

__device__ __forceinline__ short f32_to_bf16_rne(float f) {
    union { float f; unsigned int u; } c; c.f = f;
    unsigned int r = c.u + 0x7fffu + ((c.u >> 16) & 1u);
    return (short)(r >> 16);
}

// ---------------------------------------------------------------------------
// Generic tiled GEMM: Y[M,N] = act(X[M,K] @ W[N,K]^T + bias[N])
// 64x64 tile, BK=16, 256 threads, 4x4 per thread. (unchanged this round)
// ---------------------------------------------------------------------------
__global__ __launch_bounds__(256) void gemm_kernel(
    const float* __restrict__ X, const float* __restrict__ W,
    const float* __restrict__ bias, float* __restrict__ Y,
    int M, int N, int K, int relu)
{
    __shared__ float Xs[16][68];
    __shared__ float Ws[16][68];

    const int tid = threadIdx.x;
    const int tx  = tid & 15;
    const int ty  = tid >> 4;
    const int m0  = blockIdx.y * 64;
    const int n0  = blockIdx.x * 64;

    const int lr = tid >> 2;
    const int lc = (tid & 3) * 4;

    float acc[4][4] = {};

    for (int k0 = 0; k0 < K; k0 += 16) {
        float4 xv = *(const float4*)(X + (size_t)(m0 + lr) * K + k0 + lc);
        float4 wv = *(const float4*)(W + (size_t)(n0 + lr) * K + k0 + lc);
        Xs[lc + 0][lr] = xv.x; Xs[lc + 1][lr] = xv.y;
        Xs[lc + 2][lr] = xv.z; Xs[lc + 3][lr] = xv.w;
        Ws[lc + 0][lr] = wv.x; Ws[lc + 1][lr] = wv.y;
        Ws[lc + 2][lr] = wv.z; Ws[lc + 3][lr] = wv.w;
        __syncthreads();

        #pragma unroll
        for (int k = 0; k < 16; ++k) {
            float4 a = *(const float4*)&Xs[k][ty * 4];
            float4 b = *(const float4*)&Ws[k][tx * 4];
            float ar[4] = {a.x, a.y, a.z, a.w};
            float br[4] = {b.x, b.y, b.z, b.w};
            #pragma unroll
            for (int i = 0; i < 4; ++i)
                #pragma unroll
                for (int j = 0; j < 4; ++j)
                    acc[i][j] += ar[i] * br[j];
        }
        __syncthreads();
    }

    #pragma unroll
    for (int i = 0; i < 4; ++i) {
        const int gm = m0 + ty * 4 + i;
        #pragma unroll
        for (int j = 0; j < 4; ++j) {
            const int gn = n0 + tx * 4 + j;
            float v = acc[i][j] + bias[gn];
            if (relu) v = fmaxf(v, 0.f);
            Y[(size_t)gm * N + gn] = v;
        }
    }
}

// ---------------------------------------------------------------------------
// MFMA flash attention (bf16). One wave = one 16-query tile for one (b,head).
// Block = 4 waves = 64 queries. K/V staged fp32->bf16 into LDS per 128-key
// tile (K row-major stride 24; V transposed [d][key] stride 132).
// S = mfma_16x16x32(Kfrag, Qfrag) with dims zero-padded 16->32.
// PV = mfma_16x16x32 with key g*4+r placed at k_pos g*8+r so the C-layout P
// fragment is lane-locally the A-operand fragment (upper 4 slots zero).
// ---------------------------------------------------------------------------
constexpr int KT  = 128;                 // keys per LDS tile
constexpr int KS_STRIDE = 24;            // bf16 elems per K row (pad 16->24)
constexpr int VS_STRIDE = 132;           // bf16 elems per V^T row (pad 128->132)
#define LOG2E 1.4426950408889634f

__global__ __launch_bounds__(256) void attn_kernel(
    const float* __restrict__ qkv, float* __restrict__ out)
{
    __shared__ short Ks[KT * KS_STRIDE];     // [key][dim]
    __shared__ short Vs[DHh * VS_STRIDE];    // [dim][key]

    const int tid  = threadIdx.x;
    const int lane = tid & 63;
    const int wv   = tid >> 6;
    const int col  = lane & 15;              // query col / d col / key (A of S)
    const int g    = lane >> 4;              // quad
    const int hd   = blockIdx.y;
    const int b    = blockIdx.z;
    const int q0   = blockIdx.x * 64 + wv * 16;   // wave's query-tile base

    const float* base = qkv + (size_t)b * Nn * 384;

    // Q fragment (B operand of S): lane holds Q[q0+col][dims g*8..g*8+7],
    // pre-scaled by 1/sqrt(DH) * log2(e). Quads 2,3 are zero (dims 16..31).
    bf16x8 qf = {};
    if (g < 2) {
        const float* qp = base + (size_t)(q0 + col) * 384 + hd * DHh + g * 8;
        const float sc = 0.25f * LOG2E;
        #pragma unroll
        for (int i = 0; i < 8; ++i) qf[i] = f32_to_bf16_rne(qp[i] * sc);
    }

    float m = -1e30f, lsum = 0.f;            // m global; lsum partial per quad
    f32x4 o = {0.f, 0.f, 0.f, 0.f};          // O[q=g*4+r][d=col]

    // staging indices: thread -> (key row r, dim-half d0)
    const int sr = tid >> 1;
    const int sd = (tid & 1) * 8;

    for (int kt = 0; kt < Nn; kt += KT) {
        __syncthreads();
        {
            const float* kp = base + (size_t)(kt + sr) * 384 + Hh + hd * DHh + sd;
            const float* vp = kp + Hh;
            short kb[8];
            #pragma unroll
            for (int i = 0; i < 8; ++i) kb[i] = f32_to_bf16_rne(kp[i]);
            *(bf16x8*)&Ks[sr * KS_STRIDE + sd] = *(bf16x8*)kb;
            #pragma unroll
            for (int i = 0; i < 8; ++i)
                Vs[(sd + i) * VS_STRIDE + sr] = f32_to_bf16_rne(vp[i]);
        }
        __syncthreads();

        #pragma unroll
        for (int s = 0; s < KT / 16; ++s) {
            // A operand: K[key = s*16+col][dims g*8..+7]; quads 2,3 zero
            bf16x8 kf = {};
            if (g < 2)
                kf = *(bf16x8*)&Ks[(s * 16 + col) * KS_STRIDE + g * 8];

            f32x4 sfrag = {0.f, 0.f, 0.f, 0.f};
            sfrag = __builtin_amdgcn_mfma_f32_16x16x32_bf16(kf, qf, sfrag, 0, 0, 0);
            // sfrag[r] = S[key = s*16 + g*4 + r][q = col], log2-domain scores

            // online softmax
            float tmax = fmaxf(fmaxf(sfrag[0], sfrag[1]), fmaxf(sfrag[2], sfrag[3]));
            tmax = fmaxf(tmax, __shfl_xor(tmax, 16));
            tmax = fmaxf(tmax, __shfl_xor(tmax, 32));
            const float mnew  = fmaxf(m, tmax);
            const float alpha = exp2f(m - mnew);
            m = mnew;

            float p[4];
            #pragma unroll
            for (int r = 0; r < 4; ++r) p[r] = exp2f(sfrag[r] - mnew);
            lsum = lsum * alpha + ((p[0] + p[1]) + (p[2] + p[3]));

            // rescale O: alpha for query g*4+r lives at lane g*4+r
            #pragma unroll
            for (int r = 0; r < 4; ++r)
                o[r] *= __shfl(alpha, g * 4 + r);

            // P as A operand: lane's own p[r] -> slot r, upper 4 zero
            bf16x8 pf = {};
            #pragma unroll
            for (int r = 0; r < 4; ++r) pf[r] = f32_to_bf16_rne(p[r]);

            // V as B operand: B[k_pos=g*8+j][d=col] = V[key s*16+g*4+j][col]
            bf16x8 vf = {};
            *(bf16x4*)&vf = *(bf16x4*)&Vs[col * VS_STRIDE + s * 16 + g * 4];

            o = __builtin_amdgcn_mfma_f32_16x16x32_bf16(pf, vf, o, 0, 0, 0);
        }
    }

    // final l reduction across quads, then write O/l
    float lt = lsum;
    lt += __shfl_xor(lt, 16);
    lt += __shfl_xor(lt, 32);
    const float inv = 1.f / lt;              // for query = col, replicated

    #pragma unroll
    for (int r = 0; r < 4; ++r) {
        const float invr = __shfl(inv, g * 4 + r);
        out[(size_t)(b * Nn + q0 + g * 4 + r) * Hh + hd * DHh + col] = o[r] * invr;
    }
}

// ---------------------------------------------------------------------------
// h = LayerNorm(h + y) * g + b   — one wave per token
// ---------------------------------------------------------------------------
__global__ __launch_bounds__(256) void ln_residual_kernel(
    float* __restrict__ h, const float* __restrict__ y,
    const float* __restrict__ g, const float* __restrict__ be)
{
    const int lane = threadIdx.x & 63;
    const int wv   = threadIdx.x >> 6;
    const size_t t = (size_t)blockIdx.x * 4 + wv;

    float2 hv = ((const float2*)(h + t * Hh))[lane];
    float2 yv = ((const float2*)(y + t * Hh))[lane];
    float a0 = hv.x + yv.x, a1 = hv.y + yv.y;

    float sum = a0 + a1;
    #pragma unroll
    for (int off = 32; off > 0; off >>= 1) sum += __shfl_xor(sum, off);
    const float mean = sum * (1.f / 128.f);

    const float d0 = a0 - mean, d1 = a1 - mean;
    float vs = d0 * d0 + d1 * d1;
    #pragma unroll
    for (int off = 32; off > 0; off >>= 1) vs += __shfl_xor(vs, off);
    const float rstd = rsqrtf(vs * (1.f / 128.f) + 1e-5f);

    float2 gv = ((const float2*)g)[lane];
    float2 bv = ((const float2*)be)[lane];
    float2 r = { d0 * rstd * gv.x + bv.x, d1 * rstd * gv.y + bv.y };
    ((float2*)(h + t * Hh))[lane] = r;
}

// ---------------------------------------------------------------------------
// Final heads
// ---------------------------------------------------------------------------
__global__ __launch_bounds__(256) void head_kernel(
    const float* __restrict__ o1, const float* __restrict__ d1,
    const float* __restrict__ w2, const float* __restrict__ b2,
    const float* __restrict__ dw2, const float* __restrict__ db2,
    float* __restrict__ out)
{
    const int t = blockIdx.x * blockDim.x + threadIdx.x;
    const float* op = o1 + (size_t)t * 128;
    float l0 = b2[0], l1 = b2[1], l2 = b2[2];
    #pragma unroll 4
    for (int i = 0; i < 128; i += 4) {
        float4 x = *(const float4*)(op + i);
        float4 a = *(const float4*)(w2 + i);
        float4 b = *(const float4*)(w2 + 128 + i);
        float4 c = *(const float4*)(w2 + 256 + i);
        l0 += x.x*a.x + x.y*a.y + x.z*a.z + x.w*a.w;
        l1 += x.x*b.x + x.y*b.y + x.z*b.z + x.w*b.w;
        l2 += x.x*c.x + x.y*c.y + x.z*c.z + x.w*c.w;
    }
    out[(size_t)t * 3 + 0] = l0;
    out[(size_t)t * 3 + 1] = l1;
    out[(size_t)t * 3 + 2] = l2;

    const float* dp = d1 + (size_t)t * 64;
    float s = db2[0];
    #pragma unroll 4
    for (int i = 0; i < 64; i += 4) {
        float4 x = *(const float4*)(dp + i);
        float4 w = *(const float4*)(dw2 + i);
        s += x.x*w.x + x.y*w.y + x.z*w.z + x.w*w.w;
    }
    out[24576 + t] = 1.f / (1.f + __expf(-s));
}

__global__ __launch_bounds__(256) void quality_kernel(
    const float* __restrict__ prob, float* __restrict__ q)
{
    const int b = blockIdx.x;
    const int tid = threadIdx.x;
    float s = 0.f;
    for (int i = tid; i < Nn; i += 256) s += prob[(size_t)b * Nn + i];
    #pragma unroll
    for (int off = 32; off > 0; off >>= 1) s += __shfl_xor(s, off);
    __shared__ float red[4];
    if ((tid & 63) == 0) red[tid >> 6] = s;
    __syncthreads();
    if (tid == 0) q[b] = (red[0] + red[1] + red[2] + red[3]) * (1.f / (float)Nn);
}

// ---------------------------------------------------------------------------
extern "C" void kernel_launch(void* const* d_in, const int* in_sizes, int n_in,
                              void* d_out, int out_size, void* d_ws, size_t ws_size,
                              hipStream_t stream)
{
    const float* x       = (const float*)d_in[0];
    const float* fuse_w1 = (const float*)d_in[1];
    const float* fuse_b1 = (const float*)d_in[2];
    const float* fuse_w2 = (const float*)d_in[3];
    const float* fuse_b2 = (const float*)d_in[4];

    float* ws   = (float*)d_ws;
    float* h    = ws;                                  // [8192,128]
    float* bufA = ws + (size_t)MTOK * Hh;              // up to [8192,384]
    float* bufB = bufA + (size_t)MTOK * 384;           // up to [8192,256]
    float* out  = (float*)d_out;

    const dim3 blk(256);
    auto gemm = [&](const float* X, const float* W, const float* bias, float* Y,
                    int M, int N, int K, int relu) {
        dim3 grid(N / 64, M / 64);
        hipLaunchKernelGGL(gemm_kernel, grid, blk, 0, stream, X, W, bias, Y, M, N, K, relu);
    };

    // feature fusion
    gemm(x,    fuse_w1, fuse_b1, bufB, MTOK, Hh, Cc, 1);
    gemm(bufB, fuse_w2, fuse_b2, h,    MTOK, Hh, Hh, 0);

    for (int l = 0; l < 2; ++l) {
        const int base = 5 + l * 12;
        const float* in_w  = (const float*)d_in[base + 0];
        const float* in_b  = (const float*)d_in[base + 1];
        const float* out_w = (const float*)d_in[base + 2];
        const float* out_b = (const float*)d_in[base + 3];
        const float* f1w   = (const float*)d_in[base + 4];
        const float* f1b   = (const float*)d_in[base + 5];
        const float* f2w   = (const float*)d_in[base + 6];
        const float* f2b   = (const float*)d_in[base + 7];
        const float* g1    = (const float*)d_in[base + 8];
        const float* be1   = (const float*)d_in[base + 9];
        const float* g2    = (const float*)d_in[base + 10];
        const float* be2   = (const float*)d_in[base + 11];

        gemm(h, in_w, in_b, bufA, MTOK, 3 * Hh, Hh, 0);               // qkv
        hipLaunchKernelGGL(attn_kernel, dim3(Nn / 64, NHh, Bb), dim3(256), 0, stream, bufA, bufB);
        gemm(bufB, out_w, out_b, bufA, MTOK, Hh, Hh, 0);              // out proj
        hipLaunchKernelGGL(ln_residual_kernel, dim3(MTOK / 4), blk, 0, stream, h, bufA, g1, be1);
        gemm(h,    f1w, f1b, bufA, MTOK, 2 * Hh, Hh, 1);              // ffn up + relu
        gemm(bufA, f2w, f2b, bufB, MTOK, Hh, 2 * Hh, 0);              // ffn down
        hipLaunchKernelGGL(ln_residual_kernel, dim3(MTOK / 4), blk, 0, stream, h, bufB, g2, be2);
    }

    const float* out_w1 = (const float*)d_in[29];
    const float* out_b1 = (const float*)d_in[30];
    const float* out_w2 = (const float*)d_in[31];
    const float* out_b2 = (const float*)d_in[32];
    const float* det_w1 = (const float*)d_in[33];
    const float* det_b1 = (const float*)d_in[34];
    const float* det_w2 = (const float*)d_in[35];
    const float* det_b2 = (const float*)d_in[36];

    gemm(h, out_w1, out_b1, bufA, MTOK, Hh, Hh, 1);       // o1 [8192,128]
    gemm(h, det_w1, det_b1, bufB, MTOK, 64, Hh, 1);       // d1 [8192,64]
    hipLaunchKernelGGL(head_kernel, dim3(MTOK / 256), blk, 0, stream,
                       bufA, bufB, out_w2, out_b2, det_w2, det_b2, out);
    hipLaunchKernelGGL(quality_kernel, dim3(Bb), blk, 0, stream, out + 24576, out + 32768);
}

// Round 4
// 374.310 us; speedup vs baseline: 10.3852x; 1.2887x over previous
//
#include <hip/hip_runtime.h>
#include <cstddef>

constexpr int Bb  = 4;
constexpr int Nn  = 2048;
constexpr int Cc  = 256;
constexpr int Hh  = 128;
constexpr int NHh = 8;
constexpr int DHh = 16;
constexpr int MTOK = Bb * Nn;           // 8192 tokens
#define LOG2E 1.4426950408889634f

typedef __attribute__((ext_vector_type(8))) short bf16x8;
typedef __attribute__((ext_vector_type(4))) short bf16x4;
typedef __attribute__((ext_vector_type(4))) float f32x4;

__device__ __forceinline__ short f32_to_bf16_rne(float f) {
    union { float f; unsigned int u; } c; c.f = f;
    unsigned int r = c.u + 0x7fffu + ((c.u >> 16) & 1u);
    return (short)(r >> 16);
}
__device__ __forceinline__ float bf16_to_f32(short s) {
    union { float f; unsigned int u; } c; c.u = ((unsigned int)(unsigned short)s) << 16;
    return c.f;
}

// ---------------------------------------------------------------------------
// fp32 -> bf16 conversion, 13 jobs in one kernel (groups of 4 elements)
// ---------------------------------------------------------------------------
struct CvtJobs {
    const float* src[13];
    short*       dst[13];
    int          off[14];   // prefix sums in 4-element groups
};

__global__ __launch_bounds__(256) void cvt_kernel(CvtJobs j) {
    const int gid = blockIdx.x * 256 + threadIdx.x;
    if (gid >= j.off[13]) return;
    int k = 0;
    #pragma unroll
    for (int i = 0; i < 12; ++i) if (gid >= j.off[i + 1]) k = i + 1;
    const int idx = (gid - j.off[k]) * 4;
    float4 v = *(const float4*)(j.src[k] + idx);
    short o4[4] = { f32_to_bf16_rne(v.x), f32_to_bf16_rne(v.y),
                    f32_to_bf16_rne(v.z), f32_to_bf16_rne(v.w) };
    *(bf16x4*)(j.dst[k] + idx) = *(bf16x4*)o4;
}

// ---------------------------------------------------------------------------
// bf16 MFMA GEMM: Y[M,N] = act(X[M,K]@W[N,K]^T + bias). Tile 64x64, BK=32.
// 4 waves, each computes a 16(M)x64(N) strip via 4 mfma_16x16x32 per K-step.
// LDS rows padded 32->40 bf16 (80B stride: 2-way bank alias only, free).
// Yf (fp32) and/or Yb (bf16) outputs.
// ---------------------------------------------------------------------------
__global__ __launch_bounds__(256) void gemm_bf16_kernel(
    const short* __restrict__ X, const short* __restrict__ W,
    const float* __restrict__ bias, float* __restrict__ Yf,
    short* __restrict__ Yb, int M, int N, int K, int relu)
{
    __shared__ short As[64 * 40];
    __shared__ short Bs[64 * 40];

    const int tid  = threadIdx.x;
    const int lane = tid & 63;
    const int wv   = tid >> 6;
    const int col  = lane & 15;
    const int g    = lane >> 4;
    const int m0   = blockIdx.y * 64;
    const int n0   = blockIdx.x * 64;
    const int sr   = tid >> 2;          // staging row 0..63
    const int sc   = (tid & 3) * 8;     // staging k-offset {0,8,16,24}

    f32x4 acc[4] = {};

    for (int k0 = 0; k0 < K; k0 += 32) {
        __syncthreads();
        *(bf16x8*)&As[sr * 40 + sc] =
            *(const bf16x8*)(X + (size_t)(m0 + sr) * K + k0 + sc);
        *(bf16x8*)&Bs[sr * 40 + sc] =
            *(const bf16x8*)(W + (size_t)(n0 + sr) * K + k0 + sc);
        __syncthreads();

        bf16x8 a = *(bf16x8*)&As[(wv * 16 + col) * 40 + g * 8];
        #pragma unroll
        for (int jj = 0; jj < 4; ++jj) {
            bf16x8 b = *(bf16x8*)&Bs[(jj * 16 + col) * 40 + g * 8];
            acc[jj] = __builtin_amdgcn_mfma_f32_16x16x32_bf16(a, b, acc[jj], 0, 0, 0);
        }
    }

    #pragma unroll
    for (int jj = 0; jj < 4; ++jj) {
        const int cn = n0 + jj * 16 + col;
        const float bb = bias[cn];
        #pragma unroll
        for (int r = 0; r < 4; ++r) {
            const int rm = m0 + wv * 16 + g * 4 + r;
            float v = acc[jj][r] + bb;
            if (relu) v = fmaxf(v, 0.f);
            if (Yf) Yf[(size_t)rm * N + cn] = v;
            if (Yb) Yb[(size_t)rm * N + cn] = f32_to_bf16_rne(v);
        }
    }
}

// ---------------------------------------------------------------------------
// MFMA flash attention, bf16 qkv input. One wave = 16 queries of one (b,head).
// 32 keys per inner iteration: 2 S-MFMAs + 1 full-K=32 PV MFMA.
// qkv row layout [token][384] bf16 = q|k|v. Output bf16 [token][128].
// ---------------------------------------------------------------------------
constexpr int KT = 128;
constexpr int KS_STRIDE = 24;    // bf16 per K row (16 padded to 24 -> 48B)
constexpr int VS_STRIDE = 132;   // bf16 per V^T row (128 padded to 132)

__global__ __launch_bounds__(256) void attn_kernel(
    const short* __restrict__ qkv, short* __restrict__ out)
{
    __shared__ short Ks[KT * KS_STRIDE];   // [key][dim]
    __shared__ short Vs[DHh * VS_STRIDE];  // [dim][key]

    const int tid  = threadIdx.x;
    const int lane = tid & 63;
    const int wv   = tid >> 6;
    const int col  = lane & 15;
    const int g    = lane >> 4;
    const int hd   = blockIdx.y;
    const int b    = blockIdx.z;
    const int q0   = blockIdx.x * 64 + wv * 16;

    const short* base = qkv + (size_t)b * Nn * 384;

    // Q fragment (B operand of S), pre-scaled by 1/sqrt(DH)*log2(e)
    bf16x8 qf = {};
    if (g < 2) {
        bf16x8 qraw = *(const bf16x8*)(base + (size_t)(q0 + col) * 384 + hd * DHh + g * 8);
        const float sc = 0.25f * LOG2E;
        #pragma unroll
        for (int i = 0; i < 8; ++i)
            qf[i] = f32_to_bf16_rne(bf16_to_f32(qraw[i]) * sc);
    }

    float m = -1e30f, lsum = 0.f;
    f32x4 o = {0.f, 0.f, 0.f, 0.f};        // O[q=g*4+r][d=col]

    const int sr = tid >> 1;
    const int sd = (tid & 1) * 8;

    for (int kt = 0; kt < Nn; kt += KT) {
        __syncthreads();
        {
            const short* kp = base + (size_t)(kt + sr) * 384 + Hh + hd * DHh + sd;
            *(bf16x8*)&Ks[sr * KS_STRIDE + sd] = *(const bf16x8*)kp;
            bf16x8 vv = *(const bf16x8*)(kp + Hh);
            #pragma unroll
            for (int i = 0; i < 8; ++i)
                Vs[(sd + i) * VS_STRIDE + sr] = vv[i];
        }
        __syncthreads();

        #pragma unroll
        for (int s = 0; s < 4; ++s) {
            bf16x8 kf0 = {}, kf1 = {};
            if (g < 2) {
                kf0 = *(bf16x8*)&Ks[(s * 32 + col) * KS_STRIDE + g * 8];
                kf1 = *(bf16x8*)&Ks[(s * 32 + 16 + col) * KS_STRIDE + g * 8];
            }
            f32x4 sA = {0.f, 0.f, 0.f, 0.f}, sB = {0.f, 0.f, 0.f, 0.f};
            sA = __builtin_amdgcn_mfma_f32_16x16x32_bf16(kf0, qf, sA, 0, 0, 0);
            sB = __builtin_amdgcn_mfma_f32_16x16x32_bf16(kf1, qf, sB, 0, 0, 0);
            // sA[r]=S[key s*32+g*4+r][q=col], sB[r]=S[key s*32+16+g*4+r][q=col]

            float tmax = fmaxf(fmaxf(fmaxf(sA[0], sA[1]), fmaxf(sA[2], sA[3])),
                               fmaxf(fmaxf(sB[0], sB[1]), fmaxf(sB[2], sB[3])));
            tmax = fmaxf(tmax, __shfl_xor(tmax, 16));
            tmax = fmaxf(tmax, __shfl_xor(tmax, 32));
            const float mnew  = fmaxf(m, tmax);
            const float alpha = exp2f(m - mnew);
            m = mnew;

            float pA[4], pB[4];
            #pragma unroll
            for (int r = 0; r < 4; ++r) { pA[r] = exp2f(sA[r] - mnew); pB[r] = exp2f(sB[r] - mnew); }
            lsum = lsum * alpha +
                   ((pA[0] + pA[1]) + (pA[2] + pA[3]) + (pB[0] + pB[1]) + (pB[2] + pB[3]));

            #pragma unroll
            for (int r = 0; r < 4; ++r)
                o[r] *= __shfl(alpha, g * 4 + r);

            // P as A operand: key s*32+g*4+r -> k-slot g*8+r; +16 keys -> g*8+4+r
            bf16x8 pf;
            #pragma unroll
            for (int r = 0; r < 4; ++r) {
                pf[r]     = f32_to_bf16_rne(pA[r]);
                pf[4 + r] = f32_to_bf16_rne(pB[r]);
            }
            // V as B operand, matching the key->k-slot map
            bf16x8 vf;
            *(bf16x4*)&vf        = *(bf16x4*)&Vs[col * VS_STRIDE + s * 32 + g * 4];
            ((bf16x4*)&vf)[1]    = *(bf16x4*)&Vs[col * VS_STRIDE + s * 32 + 16 + g * 4];

            o = __builtin_amdgcn_mfma_f32_16x16x32_bf16(pf, vf, o, 0, 0, 0);
        }
    }

    float lt = lsum;
    lt += __shfl_xor(lt, 16);
    lt += __shfl_xor(lt, 32);
    const float inv = 1.f / lt;

    #pragma unroll
    for (int r = 0; r < 4; ++r) {
        const float invr = __shfl(inv, g * 4 + r);
        out[(size_t)(b * Nn + q0 + g * 4 + r) * Hh + hd * DHh + col] =
            f32_to_bf16_rne(o[r] * invr);
    }
}

// ---------------------------------------------------------------------------
// h = LayerNorm(h + y) * g + b — one wave per token; writes fp32 h and bf16 hb
// ---------------------------------------------------------------------------
__global__ __launch_bounds__(256) void ln_residual_kernel(
    float* __restrict__ h, const float* __restrict__ y,
    const float* __restrict__ g, const float* __restrict__ be,
    short* __restrict__ hb)
{
    const int lane = threadIdx.x & 63;
    const int wv   = threadIdx.x >> 6;
    const size_t t = (size_t)blockIdx.x * 4 + wv;

    float2 hv = ((const float2*)(h + t * Hh))[lane];
    float2 yv = ((const float2*)(y + t * Hh))[lane];
    float a0 = hv.x + yv.x, a1 = hv.y + yv.y;

    float sum = a0 + a1;
    #pragma unroll
    for (int off = 32; off > 0; off >>= 1) sum += __shfl_xor(sum, off);
    const float mean = sum * (1.f / 128.f);

    const float d0 = a0 - mean, d1 = a1 - mean;
    float vs = d0 * d0 + d1 * d1;
    #pragma unroll
    for (int off = 32; off > 0; off >>= 1) vs += __shfl_xor(vs, off);
    const float rstd = rsqrtf(vs * (1.f / 128.f) + 1e-5f);

    float2 gv = ((const float2*)g)[lane];
    float2 bv = ((const float2*)be)[lane];
    float2 r = { d0 * rstd * gv.x + bv.x, d1 * rstd * gv.y + bv.y };
    ((float2*)(h + t * Hh))[lane] = r;

    union { short s[2]; unsigned int u; } pk;
    pk.s[0] = f32_to_bf16_rne(r.x);
    pk.s[1] = f32_to_bf16_rne(r.y);
    *(unsigned int*)&hb[t * Hh + lane * 2] = pk.u;
}

// ---------------------------------------------------------------------------
// Final heads (fp32 inputs)
// ---------------------------------------------------------------------------
__global__ __launch_bounds__(256) void head_kernel(
    const float* __restrict__ o1, const float* __restrict__ d1,
    const float* __restrict__ w2, const float* __restrict__ b2,
    const float* __restrict__ dw2, const float* __restrict__ db2,
    float* __restrict__ out)
{
    const int t = blockIdx.x * blockDim.x + threadIdx.x;
    const float* op = o1 + (size_t)t * 128;
    float l0 = b2[0], l1 = b2[1], l2 = b2[2];
    #pragma unroll 4
    for (int i = 0; i < 128; i += 4) {
        float4 x = *(const float4*)(op + i);
        float4 a = *(const float4*)(w2 + i);
        float4 b = *(const float4*)(w2 + 128 + i);
        float4 c = *(const float4*)(w2 + 256 + i);
        l0 += x.x*a.x + x.y*a.y + x.z*a.z + x.w*a.w;
        l1 += x.x*b.x + x.y*b.y + x.z*b.z + x.w*b.w;
        l2 += x.x*c.x + x.y*c.y + x.z*c.z + x.w*c.w;
    }
    out[(size_t)t * 3 + 0] = l0;
    out[(size_t)t * 3 + 1] = l1;
    out[(size_t)t * 3 + 2] = l2;

    const float* dp = d1 + (size_t)t * 64;
    float s = db2[0];
    #pragma unroll 4
    for (int i = 0; i < 64; i += 4) {
        float4 x = *(const float4*)(dp + i);
        float4 w = *(const float4*)(dw2 + i);
        s += x.x*w.x + x.y*w.y + x.z*w.z + x.w*w.w;
    }
    out[24576 + t] = 1.f / (1.f + __expf(-s));
}

__global__ __launch_bounds__(256) void quality_kernel(
    const float* __restrict__ prob, float* __restrict__ q)
{
    const int b = blockIdx.x;
    const int tid = threadIdx.x;
    float s = 0.f;
    for (int i = tid; i < Nn; i += 256) s += prob[(size_t)b * Nn + i];
    #pragma unroll
    for (int off = 32; off > 0; off >>= 1) s += __shfl_xor(s, off);
    __shared__ float red[4];
    if ((tid & 63) == 0) red[tid >> 6] = s;
    __syncthreads();
    if (tid == 0) q[b] = (red[0] + red[1] + red[2] + red[3]) * (1.f / (float)Nn);
}

// ---------------------------------------------------------------------------
extern "C" void kernel_launch(void* const* d_in, const int* in_sizes, int n_in,
                              void* d_out, int out_size, void* d_ws, size_t ws_size,
                              hipStream_t stream)
{
    char* W8 = (char*)d_ws;
    float* hf   = (float*)(W8 + 0);            // 4MB  [8192,128] fp32 spine
    short* hb   = (short*)(W8 + 4194304);      // 2MB  bf16 mirror
    short* wb   = (short*)(W8 + 6291456);      // 1MB  bf16 weights
    char*  regA = W8 + 7340032;                // 6MB  xb / qkvb / ub
    char*  regB = W8 + 13631488;               // 2MB  t1b / attno
    float* yf   = (float*)(W8 + 15728640);     // 4MB  fp32 y / o1
    float* d1f  = (float*)(W8 + 19922944);     // 2MB

    short* xb    = (short*)regA;               // [8192,256]
    short* qkvb  = (short*)regA;               // [8192,384]
    short* ub    = (short*)regA;               // [8192,256]
    short* t1b   = (short*)regB;               // [8192,128]
    short* attno = (short*)regB;               // [8192,128]
    float* out   = (float*)d_out;

    // weight bf16 pool offsets
    const int wsz[12] = {32768,16384,49152,16384,32768,32768,49152,16384,32768,32768,16384,8192};
    const int wsrc[12] = {1, 3, 5, 7, 9, 11, 17, 19, 21, 23, 29, 33};
    int woff[13]; woff[0] = 0;
    for (int i = 0; i < 12; ++i) woff[i + 1] = woff[i] + wsz[i];

    CvtJobs jobs;
    int acc = 0;
    for (int i = 0; i < 12; ++i) {
        jobs.src[i] = (const float*)d_in[wsrc[i]];
        jobs.dst[i] = wb + woff[i];
        jobs.off[i] = acc;
        acc += wsz[i] / 4;
    }
    jobs.src[12] = (const float*)d_in[0];
    jobs.dst[12] = xb;
    jobs.off[12] = acc;
    acc += (MTOK * Cc) / 4;
    jobs.off[13] = acc;

    hipLaunchKernelGGL(cvt_kernel, dim3((acc + 255) / 256), dim3(256), 0, stream, jobs);

    auto gemm = [&](const short* X, const short* Wgt, const float* bias,
                    float* Yf, short* Yb, int M, int N, int K, int relu) {
        hipLaunchKernelGGL(gemm_bf16_kernel, dim3(N / 64, M / 64), dim3(256), 0, stream,
                           X, Wgt, bias, Yf, Yb, M, N, K, relu);
    };

    // feature fusion
    gemm(xb,  wb + woff[0], (const float*)d_in[2], nullptr, t1b, MTOK, Hh, Cc, 1);
    gemm(t1b, wb + woff[1], (const float*)d_in[4], hf, hb,     MTOK, Hh, Hh, 0);

    for (int l = 0; l < 2; ++l) {
        const int ib = 5 + l * 12;        // d_in base for this layer
        const int wbase = 2 + l * 4;      // wb pool base
        const float* in_b  = (const float*)d_in[ib + 1];
        const float* out_b = (const float*)d_in[ib + 3];
        const float* f1b   = (const float*)d_in[ib + 5];
        const float* f2b   = (const float*)d_in[ib + 7];
        const float* g1    = (const float*)d_in[ib + 8];
        const float* be1   = (const float*)d_in[ib + 9];
        const float* g2    = (const float*)d_in[ib + 10];
        const float* be2   = (const float*)d_in[ib + 11];

        gemm(hb, wb + woff[wbase + 0], in_b, nullptr, qkvb, MTOK, 3 * Hh, Hh, 0);
        hipLaunchKernelGGL(attn_kernel, dim3(Nn / 64, NHh, Bb), dim3(256), 0, stream,
                           qkvb, attno);
        gemm(attno, wb + woff[wbase + 1], out_b, yf, nullptr, MTOK, Hh, Hh, 0);
        hipLaunchKernelGGL(ln_residual_kernel, dim3(MTOK / 4), dim3(256), 0, stream,
                           hf, yf, g1, be1, hb);
        gemm(hb, wb + woff[wbase + 2], f1b, nullptr, ub, MTOK, 2 * Hh, Hh, 1);
        gemm(ub, wb + woff[wbase + 3], f2b, yf, nullptr, MTOK, Hh, 2 * Hh, 0);
        hipLaunchKernelGGL(ln_residual_kernel, dim3(MTOK / 4), dim3(256), 0, stream,
                           hf, yf, g2, be2, hb);
    }

    gemm(hb, wb + woff[10], (const float*)d_in[30], yf,  nullptr, MTOK, Hh, Hh, 1);  // o1
    gemm(hb, wb + woff[11], (const float*)d_in[34], d1f, nullptr, MTOK, 64, Hh, 1);  // d1
    hipLaunchKernelGGL(head_kernel, dim3(MTOK / 256), dim3(256), 0, stream,
                       yf, d1f, (const float*)d_in[31], (const float*)d_in[32],
                       (const float*)d_in[35], (const float*)d_in[36], out);
    hipLaunchKernelGGL(quality_kernel, dim3(Bb), dim3(256), 0, stream,
                       out + 24576, out + 32768);
}

// Round 5
// 362.953 us; speedup vs baseline: 10.7102x; 1.0313x over previous
//
#include <hip/hip_runtime.h>
#include <cstddef>

constexpr int Bb  = 4;
constexpr int Nn  = 2048;
constexpr int Cc  = 256;
constexpr int Hh  = 128;
constexpr int NHh = 8;
constexpr int DHh = 16;
constexpr int MTOK = Bb * Nn;           // 8192 tokens
#define LOG2E 1.4426950408889634f

typedef __attribute__((ext_vector_type(8))) short bf16x8;
typedef __attribute__((ext_vector_type(4))) short bf16x4;
typedef __attribute__((ext_vector_type(4))) float f32x4;

__device__ __forceinline__ short f32_to_bf16_rne(float f) {
    union { float f; unsigned int u; } c; c.f = f;
    unsigned int r = c.u + 0x7fffu + ((c.u >> 16) & 1u);
    return (short)(r >> 16);
}
__device__ __forceinline__ float bf16_to_f32(short s) {
    union { float f; unsigned int u; } c; c.u = ((unsigned int)(unsigned short)s) << 16;
    return c.f;
}
// pack two f32 -> two bf16 (RNE) in one u32: {hi=b, lo=a}
__device__ __forceinline__ unsigned pack2_bf16(float a, float b) {
    unsigned ua = __float_as_uint(a);
    unsigned ub = __float_as_uint(b);
    ua += 0x7fffu + ((ua >> 16) & 1u);
    ub += 0x7fffu + ((ub >> 16) & 1u);
    return __builtin_amdgcn_perm(ub, ua, 0x07060302);  // ub[3:2] : ua[3:2]
}

// ---------------------------------------------------------------------------
// fp32 -> bf16 conversion, 13 jobs in one kernel (groups of 4 elements)
// ---------------------------------------------------------------------------
struct CvtJobs {
    const float* src[13];
    short*       dst[13];
    int          off[14];   // prefix sums in 4-element groups
};

__global__ __launch_bounds__(256) void cvt_kernel(CvtJobs j) {
    const int gid = blockIdx.x * 256 + threadIdx.x;
    if (gid >= j.off[13]) return;
    int k = 0;
    #pragma unroll
    for (int i = 0; i < 12; ++i) if (gid >= j.off[i + 1]) k = i + 1;
    const int idx = (gid - j.off[k]) * 4;
    float4 v = *(const float4*)(j.src[k] + idx);
    short o4[4] = { f32_to_bf16_rne(v.x), f32_to_bf16_rne(v.y),
                    f32_to_bf16_rne(v.z), f32_to_bf16_rne(v.w) };
    *(bf16x4*)(j.dst[k] + idx) = *(bf16x4*)o4;
}

// ---------------------------------------------------------------------------
// bf16 MFMA GEMM: Y[M,N] = act(X[M,K]@W[N,K]^T + bias). Tile 128(M)x64(N),
// BK=32. 4 waves; each wave computes 32(M)x64(N) via two 16-row strips ->
// 8 mfma_16x16x32 per K-step. LDS rows padded 32->40 bf16.
// ---------------------------------------------------------------------------
__global__ __launch_bounds__(256) void gemm_bf16_kernel(
    const short* __restrict__ X, const short* __restrict__ W,
    const float* __restrict__ bias, float* __restrict__ Yf,
    short* __restrict__ Yb, int M, int N, int K, int relu)
{
    __shared__ short As[128 * 40];
    __shared__ short Bs[64 * 40];

    const int tid  = threadIdx.x;
    const int lane = tid & 63;
    const int wv   = tid >> 6;
    const int col  = lane & 15;
    const int g    = lane >> 4;
    const int m0   = blockIdx.y * 128;
    const int n0   = blockIdx.x * 64;

    const int ar = tid >> 1;            // A staging row 0..127
    const int ak = (tid & 1) * 16;      // A k-offset {0,16} (two b128s)
    const int br = tid >> 2;            // B staging row 0..63
    const int bk = (tid & 3) * 8;       // B k-offset {0,8,16,24}

    f32x4 acc0[4] = {};
    f32x4 acc1[4] = {};

    for (int k0 = 0; k0 < K; k0 += 32) {
        __syncthreads();
        const short* xp = X + (size_t)(m0 + ar) * K + k0 + ak;
        *(bf16x8*)&As[ar * 40 + ak]     = *(const bf16x8*)xp;
        *(bf16x8*)&As[ar * 40 + ak + 8] = *(const bf16x8*)(xp + 8);
        *(bf16x8*)&Bs[br * 40 + bk] =
            *(const bf16x8*)(W + (size_t)(n0 + br) * K + k0 + bk);
        __syncthreads();

        bf16x8 a0 = *(bf16x8*)&As[(wv * 32 + col) * 40 + g * 8];
        bf16x8 a1 = *(bf16x8*)&As[(wv * 32 + 16 + col) * 40 + g * 8];
        #pragma unroll
        for (int jj = 0; jj < 4; ++jj) {
            bf16x8 b = *(bf16x8*)&Bs[(jj * 16 + col) * 40 + g * 8];
            acc0[jj] = __builtin_amdgcn_mfma_f32_16x16x32_bf16(a0, b, acc0[jj], 0, 0, 0);
            acc1[jj] = __builtin_amdgcn_mfma_f32_16x16x32_bf16(a1, b, acc1[jj], 0, 0, 0);
        }
    }

    #pragma unroll
    for (int jj = 0; jj < 4; ++jj) {
        const int cn = n0 + jj * 16 + col;
        const float bb = bias[cn];
        #pragma unroll
        for (int r = 0; r < 4; ++r) {
            const int rm0 = m0 + wv * 32 + g * 4 + r;
            float v0 = acc0[jj][r] + bb;
            float v1 = acc1[jj][r] + bb;
            if (relu) { v0 = fmaxf(v0, 0.f); v1 = fmaxf(v1, 0.f); }
            if (Yf) { Yf[(size_t)rm0 * N + cn] = v0; Yf[(size_t)(rm0 + 16) * N + cn] = v1; }
            if (Yb) { Yb[(size_t)rm0 * N + cn] = f32_to_bf16_rne(v0);
                      Yb[(size_t)(rm0 + 16) * N + cn] = f32_to_bf16_rne(v1); }
        }
    }
}

// ---------------------------------------------------------------------------
// MFMA flash attention, bf16 qkv. One wave = 16 queries of one (b,head).
// Per 128-key LDS tile: 8 S-MFMAs into 32 score regs, ONE max/alpha/rescale,
// then exp + perm-pack + 4 PV MFMAs (K=32 each).
// ---------------------------------------------------------------------------
constexpr int KT = 128;
constexpr int KS = 28;     // bf16 per K row (16 padded to 28)
constexpr int VS = 132;    // bf16 per V^T row (128 padded to 132)

__global__ __launch_bounds__(256) void attn_kernel(
    const short* __restrict__ qkv, short* __restrict__ out)
{
    __shared__ short Ks[KT * KS];   // [key][dim]
    __shared__ short Vs[DHh * VS];  // [dim][key]

    const int tid  = threadIdx.x;
    const int lane = tid & 63;
    const int wv   = tid >> 6;
    const int col  = lane & 15;
    const int g    = lane >> 4;
    const int hd   = blockIdx.y;
    const int b    = blockIdx.z;
    const int q0   = blockIdx.x * 64 + wv * 16;

    const short* base = qkv + (size_t)b * Nn * 384;

    // Q fragment (B operand of S), pre-scaled by 1/sqrt(DH)*log2(e)
    bf16x8 qf = {};
    if (g < 2) {
        bf16x8 qraw = *(const bf16x8*)(base + (size_t)(q0 + col) * 384 + hd * DHh + g * 8);
        const float sc = 0.25f * LOG2E;
        #pragma unroll
        for (int i = 0; i < 8; ++i)
            qf[i] = f32_to_bf16_rne(bf16_to_f32(qraw[i]) * sc);
    }

    float m = -1e30f, lsum = 0.f;
    f32x4 o = {0.f, 0.f, 0.f, 0.f};        // O[q=g*4+r][d=col]

    // staging: K row-major (b128), V^T via pair-packed ds_write_b32
    const int ksr = tid >> 1;              // key 0..127
    const int ksd = (tid & 1) * 8;         // dim half
    const int va  = tid >> 2;              // key pair 2*va
    const int vd  = (tid & 3) * 4;         // dims vd..vd+3

    for (int kt = 0; kt < Nn; kt += KT) {
        __syncthreads();
        {
            *(bf16x8*)&Ks[ksr * KS + ksd] =
                *(const bf16x8*)(base + (size_t)(kt + ksr) * 384 + Hh + hd * DHh + ksd);
            const short* v0 = base + (size_t)(kt + 2 * va) * 384 + 2 * Hh + hd * DHh + vd;
            bf16x4 r0 = *(const bf16x4*)v0;
            bf16x4 r1 = *(const bf16x4*)(v0 + 384);
            unsigned a0 = ((const unsigned*)&r0)[0], a1 = ((const unsigned*)&r0)[1];
            unsigned b0 = ((const unsigned*)&r1)[0], b1 = ((const unsigned*)&r1)[1];
            *(unsigned*)&Vs[(vd + 0) * VS + 2 * va] = __builtin_amdgcn_perm(b0, a0, 0x05040100);
            *(unsigned*)&Vs[(vd + 1) * VS + 2 * va] = __builtin_amdgcn_perm(b0, a0, 0x07060302);
            *(unsigned*)&Vs[(vd + 2) * VS + 2 * va] = __builtin_amdgcn_perm(b1, a1, 0x05040100);
            *(unsigned*)&Vs[(vd + 3) * VS + 2 * va] = __builtin_amdgcn_perm(b1, a1, 0x07060302);
        }
        __syncthreads();

        // ---- pass 1: all scores for the 128-key tile ----
        f32x4 sc[8];
        #pragma unroll
        for (int s = 0; s < 4; ++s) {
            bf16x8 kf0 = {}, kf1 = {};
            if (g < 2) {
                kf0 = *(bf16x8*)&Ks[(s * 32 + col) * KS + g * 8];
                kf1 = *(bf16x8*)&Ks[(s * 32 + 16 + col) * KS + g * 8];
            }
            f32x4 z = {0.f, 0.f, 0.f, 0.f};
            sc[2 * s]     = __builtin_amdgcn_mfma_f32_16x16x32_bf16(kf0, qf, z, 0, 0, 0);
            sc[2 * s + 1] = __builtin_amdgcn_mfma_f32_16x16x32_bf16(kf1, qf, z, 0, 0, 0);
        }

        // ---- one softmax update per tile ----
        float tmax = sc[0][0];
        #pragma unroll
        for (int i = 0; i < 8; ++i)
            #pragma unroll
            for (int r = 0; r < 4; ++r) tmax = fmaxf(tmax, sc[i][r]);
        tmax = fmaxf(tmax, __shfl_xor(tmax, 16));
        tmax = fmaxf(tmax, __shfl_xor(tmax, 32));
        const float mnew  = fmaxf(m, tmax);
        const float alpha = exp2f(m - mnew);
        m = mnew;
        lsum *= alpha;
        #pragma unroll
        for (int r = 0; r < 4; ++r)
            o[r] *= __shfl(alpha, g * 4 + r);

        // ---- pass 2: exp, pack, PV ----
        #pragma unroll
        for (int s = 0; s < 4; ++s) {
            float pA[4], pB[4];
            #pragma unroll
            for (int r = 0; r < 4; ++r) {
                pA[r] = exp2f(sc[2 * s][r] - mnew);
                pB[r] = exp2f(sc[2 * s + 1][r] - mnew);
            }
            lsum += ((pA[0] + pA[1]) + (pA[2] + pA[3]))
                  + ((pB[0] + pB[1]) + (pB[2] + pB[3]));

            union { bf16x8 v; unsigned u[4]; } pf;
            pf.u[0] = pack2_bf16(pA[0], pA[1]);
            pf.u[1] = pack2_bf16(pA[2], pA[3]);
            pf.u[2] = pack2_bf16(pB[0], pB[1]);
            pf.u[3] = pack2_bf16(pB[2], pB[3]);

            bf16x8 vf;
            ((bf16x4*)&vf)[0] = *(bf16x4*)&Vs[col * VS + s * 32 + g * 4];
            ((bf16x4*)&vf)[1] = *(bf16x4*)&Vs[col * VS + s * 32 + 16 + g * 4];

            o = __builtin_amdgcn_mfma_f32_16x16x32_bf16(pf.v, vf, o, 0, 0, 0);
        }
    }

    float lt = lsum;
    lt += __shfl_xor(lt, 16);
    lt += __shfl_xor(lt, 32);
    const float inv = 1.f / lt;

    #pragma unroll
    for (int r = 0; r < 4; ++r) {
        const float invr = __shfl(inv, g * 4 + r);
        out[(size_t)(b * Nn + q0 + g * 4 + r) * Hh + hd * DHh + col] =
            f32_to_bf16_rne(o[r] * invr);
    }
}

// ---------------------------------------------------------------------------
// h = LayerNorm(h + y) * g + b — one wave per token; writes fp32 h and bf16 hb
// ---------------------------------------------------------------------------
__global__ __launch_bounds__(256) void ln_residual_kernel(
    float* __restrict__ h, const float* __restrict__ y,
    const float* __restrict__ g, const float* __restrict__ be,
    short* __restrict__ hb)
{
    const int lane = threadIdx.x & 63;
    const int wv   = threadIdx.x >> 6;
    const size_t t = (size_t)blockIdx.x * 4 + wv;

    float2 hv = ((const float2*)(h + t * Hh))[lane];
    float2 yv = ((const float2*)(y + t * Hh))[lane];
    float a0 = hv.x + yv.x, a1 = hv.y + yv.y;

    float sum = a0 + a1;
    #pragma unroll
    for (int off = 32; off > 0; off >>= 1) sum += __shfl_xor(sum, off);
    const float mean = sum * (1.f / 128.f);

    const float d0 = a0 - mean, d1 = a1 - mean;
    float vs = d0 * d0 + d1 * d1;
    #pragma unroll
    for (int off = 32; off > 0; off >>= 1) vs += __shfl_xor(vs, off);
    const float rstd = rsqrtf(vs * (1.f / 128.f) + 1e-5f);

    float2 gv = ((const float2*)g)[lane];
    float2 bv = ((const float2*)be)[lane];
    float2 r = { d0 * rstd * gv.x + bv.x, d1 * rstd * gv.y + bv.y };
    ((float2*)(h + t * Hh))[lane] = r;

    *(unsigned*)&hb[t * Hh + lane * 2] = pack2_bf16(r.x, r.y);
}

// ---------------------------------------------------------------------------
// Final heads (fp32 inputs)
// ---------------------------------------------------------------------------
__global__ __launch_bounds__(256) void head_kernel(
    const float* __restrict__ o1, const float* __restrict__ d1,
    const float* __restrict__ w2, const float* __restrict__ b2,
    const float* __restrict__ dw2, const float* __restrict__ db2,
    float* __restrict__ out)
{
    const int t = blockIdx.x * blockDim.x + threadIdx.x;
    const float* op = o1 + (size_t)t * 128;
    float l0 = b2[0], l1 = b2[1], l2 = b2[2];
    #pragma unroll 4
    for (int i = 0; i < 128; i += 4) {
        float4 x = *(const float4*)(op + i);
        float4 a = *(const float4*)(w2 + i);
        float4 b = *(const float4*)(w2 + 128 + i);
        float4 c = *(const float4*)(w2 + 256 + i);
        l0 += x.x*a.x + x.y*a.y + x.z*a.z + x.w*a.w;
        l1 += x.x*b.x + x.y*b.y + x.z*b.z + x.w*b.w;
        l2 += x.x*c.x + x.y*c.y + x.z*c.z + x.w*c.w;
    }
    out[(size_t)t * 3 + 0] = l0;
    out[(size_t)t * 3 + 1] = l1;
    out[(size_t)t * 3 + 2] = l2;

    const float* dp = d1 + (size_t)t * 64;
    float s = db2[0];
    #pragma unroll 4
    for (int i = 0; i < 64; i += 4) {
        float4 x = *(const float4*)(dp + i);
        float4 w = *(const float4*)(dw2 + i);
        s += x.x*w.x + x.y*w.y + x.z*w.z + x.w*w.w;
    }
    out[24576 + t] = 1.f / (1.f + __expf(-s));
}

__global__ __launch_bounds__(256) void quality_kernel(
    const float* __restrict__ prob, float* __restrict__ q)
{
    const int b = blockIdx.x;
    const int tid = threadIdx.x;
    float s = 0.f;
    for (int i = tid; i < Nn; i += 256) s += prob[(size_t)b * Nn + i];
    #pragma unroll
    for (int off = 32; off > 0; off >>= 1) s += __shfl_xor(s, off);
    __shared__ float red[4];
    if ((tid & 63) == 0) red[tid >> 6] = s;
    __syncthreads();
    if (tid == 0) q[b] = (red[0] + red[1] + red[2] + red[3]) * (1.f / (float)Nn);
}

// ---------------------------------------------------------------------------
extern "C" void kernel_launch(void* const* d_in, const int* in_sizes, int n_in,
                              void* d_out, int out_size, void* d_ws, size_t ws_size,
                              hipStream_t stream)
{
    char* W8 = (char*)d_ws;
    float* hf   = (float*)(W8 + 0);            // 4MB  [8192,128] fp32 spine
    short* hb   = (short*)(W8 + 4194304);      // 2MB  bf16 mirror
    short* wb   = (short*)(W8 + 6291456);      // 1MB  bf16 weights
    char*  regA = W8 + 7340032;                // 6MB  xb / qkvb / ub
    char*  regB = W8 + 13631488;               // 2MB  t1b / attno
    float* yf   = (float*)(W8 + 15728640);     // 4MB  fp32 y / o1
    float* d1f  = (float*)(W8 + 19922944);     // 2MB

    short* xb    = (short*)regA;               // [8192,256]
    short* qkvb  = (short*)regA;               // [8192,384]
    short* ub    = (short*)regA;               // [8192,256]
    short* t1b   = (short*)regB;               // [8192,128]
    short* attno = (short*)regB;               // [8192,128]
    float* out   = (float*)d_out;

    // weight bf16 pool offsets
    const int wsz[12] = {32768,16384,49152,16384,32768,32768,49152,16384,32768,32768,16384,8192};
    const int wsrc[12] = {1, 3, 5, 7, 9, 11, 17, 19, 21, 23, 29, 33};
    int woff[13]; woff[0] = 0;
    for (int i = 0; i < 12; ++i) woff[i + 1] = woff[i] + wsz[i];

    CvtJobs jobs;
    int acc = 0;
    for (int i = 0; i < 12; ++i) {
        jobs.src[i] = (const float*)d_in[wsrc[i]];
        jobs.dst[i] = wb + woff[i];
        jobs.off[i] = acc;
        acc += wsz[i] / 4;
    }
    jobs.src[12] = (const float*)d_in[0];
    jobs.dst[12] = xb;
    jobs.off[12] = acc;
    acc += (MTOK * Cc) / 4;
    jobs.off[13] = acc;

    hipLaunchKernelGGL(cvt_kernel, dim3((acc + 255) / 256), dim3(256), 0, stream, jobs);

    auto gemm = [&](const short* X, const short* Wgt, const float* bias,
                    float* Yf, short* Yb, int M, int N, int K, int relu) {
        hipLaunchKernelGGL(gemm_bf16_kernel, dim3(N / 64, M / 128), dim3(256), 0, stream,
                           X, Wgt, bias, Yf, Yb, M, N, K, relu);
    };

    // feature fusion
    gemm(xb,  wb + woff[0], (const float*)d_in[2], nullptr, t1b, MTOK, Hh, Cc, 1);
    gemm(t1b, wb + woff[1], (const float*)d_in[4], hf, hb,     MTOK, Hh, Hh, 0);

    for (int l = 0; l < 2; ++l) {
        const int ib = 5 + l * 12;        // d_in base for this layer
        const int wbase = 2 + l * 4;      // wb pool base
        const float* in_b  = (const float*)d_in[ib + 1];
        const float* out_b = (const float*)d_in[ib + 3];
        const float* f1b   = (const float*)d_in[ib + 5];
        const float* f2b   = (const float*)d_in[ib + 7];
        const float* g1    = (const float*)d_in[ib + 8];
        const float* be1   = (const float*)d_in[ib + 9];
        const float* g2    = (const float*)d_in[ib + 10];
        const float* be2   = (const float*)d_in[ib + 11];

        gemm(hb, wb + woff[wbase + 0], in_b, nullptr, qkvb, MTOK, 3 * Hh, Hh, 0);
        hipLaunchKernelGGL(attn_kernel, dim3(Nn / 64, NHh, Bb), dim3(256), 0, stream,
                           qkvb, attno);
        gemm(attno, wb + woff[wbase + 1], out_b, yf, nullptr, MTOK, Hh, Hh, 0);
        hipLaunchKernelGGL(ln_residual_kernel, dim3(MTOK / 4), dim3(256), 0, stream,
                           hf, yf, g1, be1, hb);
        gemm(hb, wb + woff[wbase + 2], f1b, nullptr, ub, MTOK, 2 * Hh, Hh, 1);
        gemm(ub, wb + woff[wbase + 3], f2b, yf, nullptr, MTOK, Hh, 2 * Hh, 0);
        hipLaunchKernelGGL(ln_residual_kernel, dim3(MTOK / 4), dim3(256), 0, stream,
                           hf, yf, g2, be2, hb);
    }

    gemm(hb, wb + woff[10], (const float*)d_in[30], yf,  nullptr, MTOK, Hh, Hh, 1);  // o1
    gemm(hb, wb + woff[11], (const float*)d_in[34], d1f, nullptr, MTOK, 64, Hh, 1);  // d1
    hipLaunchKernelGGL(head_kernel, dim3(MTOK / 256), dim3(256), 0, stream,
                       yf, d1f, (const float*)d_in[31], (const float*)d_in[32],
                       (const float*)d_in[35], (const float*)d_in[36], out);
    hipLaunchKernelGGL(quality_kernel, dim3(Bb), dim3(256), 0, stream,
                       out + 24576, out + 32768);
}

// Round 7
// 356.806 us; speedup vs baseline: 10.8947x; 1.0172x over previous
//
#include <hip/hip_runtime.h>
#include <cstddef>

constexpr int Bb  = 4;
constexpr int Nn  = 2048;
constexpr int Cc  = 256;
constexpr int Hh  = 128;
constexpr int NHh = 8;
constexpr int DHh = 16;
constexpr int MTOK = Bb * Nn;           // 8192 tokens
#define LOG2E 1.4426950408889634f

typedef __attribute__((ext_vector_type(8))) short bf16x8;
typedef __attribute__((ext_vector_type(4))) short bf16x4;
typedef __attribute__((ext_vector_type(4))) float f32x4;

__device__ __forceinline__ short f32_to_bf16_rne(float f) {
    union { float f; unsigned int u; } c; c.f = f;
    unsigned int r = c.u + 0x7fffu + ((c.u >> 16) & 1u);
    return (short)(r >> 16);
}
__device__ __forceinline__ float bf16_to_f32(short s) {
    union { float f; unsigned int u; } c; c.u = ((unsigned int)(unsigned short)s) << 16;
    return c.f;
}
__device__ __forceinline__ unsigned pack2_bf16(float a, float b) {
    unsigned ua = __float_as_uint(a);
    unsigned ub = __float_as_uint(b);
    ua += 0x7fffu + ((ua >> 16) & 1u);
    ub += 0x7fffu + ((ub >> 16) & 1u);
    return __builtin_amdgcn_perm(ub, ua, 0x07060302);
}

// ---------------------------------------------------------------------------
// fp32 -> bf16 conversion, 13 jobs in one kernel (groups of 4 elements)
// ---------------------------------------------------------------------------
struct CvtJobs {
    const float* src[13];
    short*       dst[13];
    int          off[14];   // prefix sums in 4-element groups
};

__global__ __launch_bounds__(256) void cvt_kernel(CvtJobs j) {
    const int gid = blockIdx.x * 256 + threadIdx.x;
    if (gid >= j.off[13]) return;
    int k = 0;
    #pragma unroll
    for (int i = 0; i < 12; ++i) if (gid >= j.off[i + 1]) k = i + 1;
    const int idx = (gid - j.off[k]) * 4;
    float4 v = *(const float4*)(j.src[k] + idx);
    short o4[4] = { f32_to_bf16_rne(v.x), f32_to_bf16_rne(v.y),
                    f32_to_bf16_rne(v.z), f32_to_bf16_rne(v.w) };
    *(bf16x4*)(j.dst[k] + idx) = *(bf16x4*)o4;
}

// ---------------------------------------------------------------------------
// bf16 MFMA GEMM (R3-verified): 64x64 tile, BK=32, 4 waves, each a 16x64
// strip via 4 mfma_16x16x32 per K-step. LDS rows padded 32->40 bf16.
// ---------------------------------------------------------------------------
__global__ __launch_bounds__(256) void gemm_bf16_kernel(
    const short* __restrict__ X, const short* __restrict__ W,
    const float* __restrict__ bias, float* __restrict__ Yf,
    short* __restrict__ Yb, int M, int N, int K, int relu)
{
    __shared__ short As[64 * 40];
    __shared__ short Bs[64 * 40];

    const int tid  = threadIdx.x;
    const int lane = tid & 63;
    const int wv   = tid >> 6;
    const int col  = lane & 15;
    const int g    = lane >> 4;
    const int m0   = blockIdx.y * 64;
    const int n0   = blockIdx.x * 64;
    const int sr   = tid >> 2;
    const int sc   = (tid & 3) * 8;

    f32x4 acc[4] = {};

    for (int k0 = 0; k0 < K; k0 += 32) {
        __syncthreads();
        *(bf16x8*)&As[sr * 40 + sc] =
            *(const bf16x8*)(X + (size_t)(m0 + sr) * K + k0 + sc);
        *(bf16x8*)&Bs[sr * 40 + sc] =
            *(const bf16x8*)(W + (size_t)(n0 + sr) * K + k0 + sc);
        __syncthreads();

        bf16x8 a = *(bf16x8*)&As[(wv * 16 + col) * 40 + g * 8];
        #pragma unroll
        for (int jj = 0; jj < 4; ++jj) {
            bf16x8 b = *(bf16x8*)&Bs[(jj * 16 + col) * 40 + g * 8];
            acc[jj] = __builtin_amdgcn_mfma_f32_16x16x32_bf16(a, b, acc[jj], 0, 0, 0);
        }
    }

    #pragma unroll
    for (int jj = 0; jj < 4; ++jj) {
        const int cn = n0 + jj * 16 + col;
        const float bb = bias[cn];
        #pragma unroll
        for (int r = 0; r < 4; ++r) {
            const int rm = m0 + wv * 16 + g * 4 + r;
            float v = acc[jj][r] + bb;
            if (relu) v = fmaxf(v, 0.f);
            if (Yf) Yf[(size_t)rm * N + cn] = v;
            if (Yb) Yb[(size_t)rm * N + cn] = f32_to_bf16_rne(v);
        }
    }
}

// ---------------------------------------------------------------------------
// MFMA flash attention (R4-verified), bf16 qkv. One wave = 16 queries of one
// (b,head). Per 128-key LDS tile: 8 S-MFMAs into 32 score regs, ONE
// max/alpha/rescale, then exp + perm-pack + 4 PV MFMAs (K=32 each).
// ---------------------------------------------------------------------------
constexpr int KT = 128;
constexpr int KS = 28;     // bf16 per K row (16 padded to 28)
constexpr int VS = 132;    // bf16 per V^T row (128 padded to 132)

__global__ __launch_bounds__(256) void attn_kernel(
    const short* __restrict__ qkv, short* __restrict__ out)
{
    __shared__ short Ks[KT * KS];   // [key][dim]
    __shared__ short Vs[DHh * VS];  // [dim][key]

    const int tid  = threadIdx.x;
    const int lane = tid & 63;
    const int wv   = tid >> 6;
    const int col  = lane & 15;
    const int g    = lane >> 4;
    const int hd   = blockIdx.y;
    const int b    = blockIdx.z;
    const int q0   = blockIdx.x * 64 + wv * 16;

    const short* base = qkv + (size_t)b * Nn * 384;

    // Q fragment (B operand of S), pre-scaled by 1/sqrt(DH)*log2(e)
    bf16x8 qf = {};
    if (g < 2) {
        bf16x8 qraw = *(const bf16x8*)(base + (size_t)(q0 + col) * 384 + hd * DHh + g * 8);
        const float qs = 0.25f * LOG2E;
        #pragma unroll
        for (int i = 0; i < 8; ++i)
            qf[i] = f32_to_bf16_rne(bf16_to_f32(qraw[i]) * qs);
    }

    float m = -1e30f, lsum = 0.f;
    f32x4 o = {0.f, 0.f, 0.f, 0.f};        // O[q=g*4+r][d=col]

    const int ksr = tid >> 1;              // key 0..127
    const int ksd = (tid & 1) * 8;         // dim half
    const int va  = tid >> 2;              // key pair 2*va
    const int vd  = (tid & 3) * 4;         // dims vd..vd+3

    for (int kt = 0; kt < Nn; kt += KT) {
        __syncthreads();
        {
            *(bf16x8*)&Ks[ksr * KS + ksd] =
                *(const bf16x8*)(base + (size_t)(kt + ksr) * 384 + Hh + hd * DHh + ksd);
            const short* v0 = base + (size_t)(kt + 2 * va) * 384 + 2 * Hh + hd * DHh + vd;
            bf16x4 r0 = *(const bf16x4*)v0;
            bf16x4 r1 = *(const bf16x4*)(v0 + 384);
            unsigned a0 = ((const unsigned*)&r0)[0], a1 = ((const unsigned*)&r0)[1];
            unsigned b0 = ((const unsigned*)&r1)[0], b1 = ((const unsigned*)&r1)[1];
            *(unsigned*)&Vs[(vd + 0) * VS + 2 * va] = __builtin_amdgcn_perm(b0, a0, 0x05040100);
            *(unsigned*)&Vs[(vd + 1) * VS + 2 * va] = __builtin_amdgcn_perm(b0, a0, 0x07060302);
            *(unsigned*)&Vs[(vd + 2) * VS + 2 * va] = __builtin_amdgcn_perm(b1, a1, 0x05040100);
            *(unsigned*)&Vs[(vd + 3) * VS + 2 * va] = __builtin_amdgcn_perm(b1, a1, 0x07060302);
        }
        __syncthreads();

        // ---- pass 1: all scores for the 128-key tile ----
        f32x4 scr[8];
        #pragma unroll
        for (int s = 0; s < 4; ++s) {
            bf16x8 kf0 = {}, kf1 = {};
            if (g < 2) {
                kf0 = *(bf16x8*)&Ks[(s * 32 + col) * KS + g * 8];
                kf1 = *(bf16x8*)&Ks[(s * 32 + 16 + col) * KS + g * 8];
            }
            f32x4 z = {0.f, 0.f, 0.f, 0.f};
            scr[2 * s]     = __builtin_amdgcn_mfma_f32_16x16x32_bf16(kf0, qf, z, 0, 0, 0);
            scr[2 * s + 1] = __builtin_amdgcn_mfma_f32_16x16x32_bf16(kf1, qf, z, 0, 0, 0);
        }

        // ---- one softmax update per tile ----
        float tmax = scr[0][0];
        #pragma unroll
        for (int i = 0; i < 8; ++i)
            #pragma unroll
            for (int r = 0; r < 4; ++r) tmax = fmaxf(tmax, scr[i][r]);
        tmax = fmaxf(tmax, __shfl_xor(tmax, 16));
        tmax = fmaxf(tmax, __shfl_xor(tmax, 32));
        const float mnew  = fmaxf(m, tmax);
        const float alpha = exp2f(m - mnew);
        m = mnew;
        lsum *= alpha;
        #pragma unroll
        for (int r = 0; r < 4; ++r)
            o[r] *= __shfl(alpha, g * 4 + r);

        // ---- pass 2: exp, pack, PV ----
        #pragma unroll
        for (int s = 0; s < 4; ++s) {
            float pA[4], pB[4];
            #pragma unroll
            for (int r = 0; r < 4; ++r) {
                pA[r] = exp2f(scr[2 * s][r] - mnew);
                pB[r] = exp2f(scr[2 * s + 1][r] - mnew);
            }
            lsum += ((pA[0] + pA[1]) + (pA[2] + pA[3]))
                  + ((pB[0] + pB[1]) + (pB[2] + pB[3]));

            union { bf16x8 v; unsigned u[4]; } pf;
            pf.u[0] = pack2_bf16(pA[0], pA[1]);
            pf.u[1] = pack2_bf16(pA[2], pA[3]);
            pf.u[2] = pack2_bf16(pB[0], pB[1]);
            pf.u[3] = pack2_bf16(pB[2], pB[3]);

            bf16x8 vf;
            ((bf16x4*)&vf)[0] = *(bf16x4*)&Vs[col * VS + s * 32 + g * 4];
            ((bf16x4*)&vf)[1] = *(bf16x4*)&Vs[col * VS + s * 32 + 16 + g * 4];

            o = __builtin_amdgcn_mfma_f32_16x16x32_bf16(pf.v, vf, o, 0, 0, 0);
        }
    }

    float lt = lsum;
    lt += __shfl_xor(lt, 16);
    lt += __shfl_xor(lt, 32);
    const float inv = 1.f / lt;

    #pragma unroll
    for (int r = 0; r < 4; ++r) {
        const float invr = __shfl(inv, g * 4 + r);
        out[(size_t)(b * Nn + q0 + g * 4 + r) * Hh + hd * DHh + col] =
            f32_to_bf16_rne(o[r] * invr);
    }
}

// ---------------------------------------------------------------------------
// h = LayerNorm(h + y) * g + b — one wave per token; writes fp32 h and bf16 hb
// ---------------------------------------------------------------------------
__global__ __launch_bounds__(256) void ln_residual_kernel(
    float* __restrict__ h, const float* __restrict__ y,
    const float* __restrict__ g, const float* __restrict__ be,
    short* __restrict__ hb)
{
    const int lane = threadIdx.x & 63;
    const int wv   = threadIdx.x >> 6;
    const size_t t = (size_t)blockIdx.x * 4 + wv;

    float2 hv = ((const float2*)(h + t * Hh))[lane];
    float2 yv = ((const float2*)(y + t * Hh))[lane];
    float a0 = hv.x + yv.x, a1 = hv.y + yv.y;

    float sum = a0 + a1;
    #pragma unroll
    for (int off = 32; off > 0; off >>= 1) sum += __shfl_xor(sum, off);
    const float mean = sum * (1.f / 128.f);

    const float d0 = a0 - mean, d1 = a1 - mean;
    float vs = d0 * d0 + d1 * d1;
    #pragma unroll
    for (int off = 32; off > 0; off >>= 1) vs += __shfl_xor(vs, off);
    const float rstd = rsqrtf(vs * (1.f / 128.f) + 1e-5f);

    float2 gv = ((const float2*)g)[lane];
    float2 bv = ((const float2*)be)[lane];
    float2 r = { d0 * rstd * gv.x + bv.x, d1 * rstd * gv.y + bv.y };
    ((float2*)(h + t * Hh))[lane] = r;

    *(unsigned*)&hb[t * Hh + lane * 2] = pack2_bf16(r.x, r.y);
}

// ---------------------------------------------------------------------------
// Final heads (fp32 inputs) — R4-verified
// ---------------------------------------------------------------------------
__global__ __launch_bounds__(256) void head_kernel(
    const float* __restrict__ o1, const float* __restrict__ d1,
    const float* __restrict__ w2, const float* __restrict__ b2,
    const float* __restrict__ dw2, const float* __restrict__ db2,
    float* __restrict__ out)
{
    const int t = blockIdx.x * blockDim.x + threadIdx.x;
    const float* op = o1 + (size_t)t * 128;
    float l0 = b2[0], l1 = b2[1], l2 = b2[2];
    #pragma unroll 4
    for (int i = 0; i < 128; i += 4) {
        float4 x = *(const float4*)(op + i);
        float4 a = *(const float4*)(w2 + i);
        float4 b = *(const float4*)(w2 + 128 + i);
        float4 c = *(const float4*)(w2 + 256 + i);
        l0 += x.x*a.x + x.y*a.y + x.z*a.z + x.w*a.w;
        l1 += x.x*b.x + x.y*b.y + x.z*b.z + x.w*b.w;
        l2 += x.x*c.x + x.y*c.y + x.z*c.z + x.w*c.w;
    }
    out[(size_t)t * 3 + 0] = l0;
    out[(size_t)t * 3 + 1] = l1;
    out[(size_t)t * 3 + 2] = l2;

    const float* dp = d1 + (size_t)t * 64;
    float s = db2[0];
    #pragma unroll 4
    for (int i = 0; i < 64; i += 4) {
        float4 x = *(const float4*)(dp + i);
        float4 w = *(const float4*)(dw2 + i);
        s += x.x*w.x + x.y*w.y + x.z*w.z + x.w*w.w;
    }
    out[24576 + t] = 1.f / (1.f + __expf(-s));
}

__global__ __launch_bounds__(256) void quality_kernel(
    const float* __restrict__ prob, float* __restrict__ q)
{
    const int b = blockIdx.x;
    const int tid = threadIdx.x;
    float s = 0.f;
    for (int i = tid; i < Nn; i += 256) s += prob[(size_t)b * Nn + i];
    #pragma unroll
    for (int off = 32; off > 0; off >>= 1) s += __shfl_xor(s, off);
    __shared__ float red[4];
    if ((tid & 63) == 0) red[tid >> 6] = s;
    __syncthreads();
    if (tid == 0) q[b] = (red[0] + red[1] + red[2] + red[3]) * (1.f / (float)Nn);
}

// ---------------------------------------------------------------------------
extern "C" void kernel_launch(void* const* d_in, const int* in_sizes, int n_in,
                              void* d_out, int out_size, void* d_ws, size_t ws_size,
                              hipStream_t stream)
{
    char* W8 = (char*)d_ws;
    float* hf   = (float*)(W8 + 0);            // 4MB  fp32 residual spine
    short* hb   = (short*)(W8 + 4194304);      // 2MB  bf16 mirror
    short* wb   = (short*)(W8 + 6291456);      // 1MB  bf16 weights
    char*  regA = W8 + 7340032;                // 6MB  xb / qkvb / ub
    char*  regB = W8 + 13631488;               // 2MB  t1b / attno
    float* yf   = (float*)(W8 + 15728640);     // 4MB  fp32 y / o1
    float* d1f  = (float*)(W8 + 19922944);     // 2MB

    short* xb    = (short*)regA;               // [8192,256]
    short* qkvb  = (short*)regA;               // [8192,384]
    short* ub    = (short*)regA;               // [8192,256]
    short* t1b   = (short*)regB;               // [8192,128]
    short* attno = (short*)regB;               // [8192,128]
    float* out   = (float*)d_out;

    const int wsz[12]  = {32768,16384,49152,16384,32768,32768,49152,16384,32768,32768,16384,8192};
    const int wsrc[12] = {1, 3, 5, 7, 9, 11, 17, 19, 21, 23, 29, 33};
    int woff[13]; woff[0] = 0;
    for (int i = 0; i < 12; ++i) woff[i + 1] = woff[i] + wsz[i];

    CvtJobs jobs;
    int acc = 0;
    for (int i = 0; i < 12; ++i) {
        jobs.src[i] = (const float*)d_in[wsrc[i]];
        jobs.dst[i] = wb + woff[i];
        jobs.off[i] = acc;
        acc += wsz[i] / 4;
    }
    jobs.src[12] = (const float*)d_in[0];
    jobs.dst[12] = xb;
    jobs.off[12] = acc;
    acc += (MTOK * Cc) / 4;
    jobs.off[13] = acc;

    hipLaunchKernelGGL(cvt_kernel, dim3((acc + 255) / 256), dim3(256), 0, stream, jobs);

    auto gemm = [&](const short* X, const short* Wgt, const float* bias,
                    float* Yf, short* Yb, int M, int N, int K, int relu) {
        hipLaunchKernelGGL(gemm_bf16_kernel, dim3(N / 64, M / 64), dim3(256), 0, stream,
                           X, Wgt, bias, Yf, Yb, M, N, K, relu);
    };

    // feature fusion
    gemm(xb,  wb + woff[0], (const float*)d_in[2], nullptr, t1b, MTOK, Hh, Cc, 1);
    gemm(t1b, wb + woff[1], (const float*)d_in[4], hf, hb,     MTOK, Hh, Hh, 0);

    for (int l = 0; l < 2; ++l) {
        const int ib = 5 + l * 12;
        const int wbase = 2 + l * 4;
        gemm(hb, wb + woff[wbase + 0], (const float*)d_in[ib + 1], nullptr, qkvb,
             MTOK, 3 * Hh, Hh, 0);
        hipLaunchKernelGGL(attn_kernel, dim3(Nn / 64, NHh, Bb), dim3(256), 0, stream,
                           qkvb, attno);
        gemm(attno, wb + woff[wbase + 1], (const float*)d_in[ib + 3], yf, nullptr,
             MTOK, Hh, Hh, 0);
        hipLaunchKernelGGL(ln_residual_kernel, dim3(MTOK / 4), dim3(256), 0, stream,
                           hf, yf, (const float*)d_in[ib + 8], (const float*)d_in[ib + 9], hb);
        gemm(hb, wb + woff[wbase + 2], (const float*)d_in[ib + 5], nullptr, ub,
             MTOK, 2 * Hh, Hh, 1);
        gemm(ub, wb + woff[wbase + 3], (const float*)d_in[ib + 7], yf, nullptr,
             MTOK, Hh, 2 * Hh, 0);
        hipLaunchKernelGGL(ln_residual_kernel, dim3(MTOK / 4), dim3(256), 0, stream,
                           hf, yf, (const float*)d_in[ib + 10], (const float*)d_in[ib + 11], hb);
    }

    gemm(hb, wb + woff[10], (const float*)d_in[30], yf,  nullptr, MTOK, Hh, Hh, 1);  // o1
    gemm(hb, wb + woff[11], (const float*)d_in[34], d1f, nullptr, MTOK, 64, Hh, 1);  // d1
    hipLaunchKernelGGL(head_kernel, dim3(MTOK / 256), dim3(256), 0, stream,
                       yf, d1f, (const float*)d_in[31], (const float*)d_in[32],
                       (const float*)d_in[35], (const float*)d_in[36], out);
    hipLaunchKernelGGL(quality_kernel, dim3(Bb), dim3(256), 0, stream,
                       out + 24576, out + 32768);
}

// Round 8
// 351.766 us; speedup vs baseline: 11.0508x; 1.0143x over previous
//
#include <hip/hip_runtime.h>
#include <cstddef>

constexpr int Bb  = 4;
constexpr int Nn  = 2048;
constexpr int Cc  = 256;
constexpr int Hh  = 128;
constexpr int NHh = 8;
constexpr int DHh = 16;
constexpr int MTOK = Bb * Nn;           // 8192 tokens
#define LOG2E 1.4426950408889634f

typedef __attribute__((ext_vector_type(8))) short bf16x8;
typedef __attribute__((ext_vector_type(4))) short bf16x4;
typedef __attribute__((ext_vector_type(4))) float f32x4;

__device__ __forceinline__ short f32_to_bf16_rne(float f) {
    union { float f; unsigned int u; } c; c.f = f;
    unsigned int r = c.u + 0x7fffu + ((c.u >> 16) & 1u);
    return (short)(r >> 16);
}
__device__ __forceinline__ float bf16_to_f32(short s) {
    union { float f; unsigned int u; } c; c.u = ((unsigned int)(unsigned short)s) << 16;
    return c.f;
}
__device__ __forceinline__ unsigned pack2_bf16(float a, float b) {
    unsigned ua = __float_as_uint(a);
    unsigned ub = __float_as_uint(b);
    ua += 0x7fffu + ((ua >> 16) & 1u);
    ub += 0x7fffu + ((ub >> 16) & 1u);
    return __builtin_amdgcn_perm(ub, ua, 0x07060302);
}

// ---------------------------------------------------------------------------
// fp32 -> bf16 conversion (weights + x) + zero the 4 quality accumulators
// ---------------------------------------------------------------------------
struct CvtJobs {
    const float* src[13];
    short*       dst[13];
    int          off[14];
    float*       qzero;
};

__global__ __launch_bounds__(256) void cvt_kernel(CvtJobs j) {
    const int gid = blockIdx.x * 256 + threadIdx.x;
    if (blockIdx.x == 0 && threadIdx.x < 4) j.qzero[threadIdx.x] = 0.f;
    if (gid >= j.off[13]) return;
    int k = 0;
    #pragma unroll
    for (int i = 0; i < 12; ++i) if (gid >= j.off[i + 1]) k = i + 1;
    const int idx = (gid - j.off[k]) * 4;
    float4 v = *(const float4*)(j.src[k] + idx);
    short o4[4] = { f32_to_bf16_rne(v.x), f32_to_bf16_rne(v.y),
                    f32_to_bf16_rne(v.z), f32_to_bf16_rne(v.w) };
    *(bf16x4*)(j.dst[k] + idx) = *(bf16x4*)o4;
}

// ---------------------------------------------------------------------------
// Plain bf16 MFMA GEMM (R3/R6-verified): 64x64 tile, BK=32, 4 waves.
// ---------------------------------------------------------------------------
__global__ __launch_bounds__(256) void gemm_bf16_kernel(
    const short* __restrict__ X, const short* __restrict__ W,
    const float* __restrict__ bias, short* __restrict__ Yb,
    int M, int N, int K, int relu)
{
    __shared__ short As[64 * 40];
    __shared__ short Bs[64 * 40];

    const int tid  = threadIdx.x;
    const int lane = tid & 63;
    const int wv   = tid >> 6;
    const int col  = lane & 15;
    const int g    = lane >> 4;
    const int m0   = blockIdx.y * 64;
    const int n0   = blockIdx.x * 64;
    const int sr   = tid >> 2;
    const int sc   = (tid & 3) * 8;

    f32x4 acc[4] = {};

    for (int k0 = 0; k0 < K; k0 += 32) {
        __syncthreads();
        *(bf16x8*)&As[sr * 40 + sc] =
            *(const bf16x8*)(X + (size_t)(m0 + sr) * K + k0 + sc);
        *(bf16x8*)&Bs[sr * 40 + sc] =
            *(const bf16x8*)(W + (size_t)(n0 + sr) * K + k0 + sc);
        __syncthreads();

        bf16x8 a = *(bf16x8*)&As[(wv * 16 + col) * 40 + g * 8];
        #pragma unroll
        for (int jj = 0; jj < 4; ++jj) {
            bf16x8 b = *(bf16x8*)&Bs[(jj * 16 + col) * 40 + g * 8];
            acc[jj] = __builtin_amdgcn_mfma_f32_16x16x32_bf16(a, b, acc[jj], 0, 0, 0);
        }
    }

    #pragma unroll
    for (int jj = 0; jj < 4; ++jj) {
        const int cn = n0 + jj * 16 + col;
        const float bb = bias[cn];
        #pragma unroll
        for (int r = 0; r < 4; ++r) {
            const int rm = m0 + wv * 16 + g * 4 + r;
            float v = acc[jj][r] + bb;
            if (relu) v = fmaxf(v, 0.f);
            Yb[(size_t)rm * N + cn] = f32_to_bf16_rne(v);
        }
    }
}

// ---------------------------------------------------------------------------
// Fused GEMM(+bias) + residual + LayerNorm. Block = 32 rows x 128 cols.
// NO LDS ALIASING: separate As / Ws / P arrays. W streamed in CR-row chunks.
// K=128 -> CR=64 (42.8 KB LDS); K=256 -> CR=32 (50.4 KB LDS).
// DO_LN=false: plain write of hf+hb (feature-fusion stage 2).
// ---------------------------------------------------------------------------
template<int K, int CR, bool DO_LN>
__global__ __launch_bounds__(256) void gemmln_kernel(
    const short* __restrict__ X, const short* __restrict__ W,
    const float* __restrict__ bias,
    float* __restrict__ hf, short* __restrict__ hb,
    const float* __restrict__ gw, const float* __restrict__ bw)
{
    constexpr int ST  = K + 8;
    constexpr int NCH = 128 / CR;   // W chunks
    constexpr int NF  = CR / 32;    // 16-col fragments per wave per chunk
    __shared__ short As[32 * ST];
    __shared__ short Ws[CR * ST];
    __shared__ float P[32 * 130];

    const int tid  = threadIdx.x;
    const int lane = tid & 63;
    const int wv   = tid >> 6;
    const int col  = lane & 15;
    const int g    = lane >> 4;
    const int m0   = blockIdx.x * 32;
    const int mst  = (wv & 1) * 16;            // wave's 16-row strip
    const int cb   = (wv >> 1) * (CR / 2);     // wave's col base within chunk

    // stage A rows (32 x K)
    for (int i = tid; i < 32 * (K / 8); i += 256) {
        const int r = i / (K / 8), c = (i % (K / 8)) * 8;
        *(bf16x8*)&As[r * ST + c] = *(const bf16x8*)(X + (size_t)(m0 + r) * K + c);
    }

    f32x4 ya[NCH][NF] = {};
    #pragma unroll
    for (int ch = 0; ch < NCH; ++ch) {
        for (int i = tid; i < CR * (K / 8); i += 256) {
            const int r = i / (K / 8), c = (i % (K / 8)) * 8;
            *(bf16x8*)&Ws[r * ST + c] =
                *(const bf16x8*)(W + (size_t)(ch * CR + r) * K + c);
        }
        __syncthreads();
        #pragma unroll
        for (int k0 = 0; k0 < K; k0 += 32) {
            bf16x8 a = *(bf16x8*)&As[(mst + col) * ST + k0 + g * 8];
            #pragma unroll
            for (int f = 0; f < NF; ++f) {
                bf16x8 b = *(bf16x8*)&Ws[(cb + f * 16 + col) * ST + k0 + g * 8];
                ya[ch][f] = __builtin_amdgcn_mfma_f32_16x16x32_bf16(a, b, ya[ch][f], 0, 0, 0);
            }
        }
        __syncthreads();
    }

    // scatter accumulators (+bias) to P
    #pragma unroll
    for (int ch = 0; ch < NCH; ++ch)
        #pragma unroll
        for (int f = 0; f < NF; ++f) {
            const int cn = ch * CR + cb + f * 16 + col;
            const float bb = bias[cn];
            #pragma unroll
            for (int r = 0; r < 4; ++r)
                P[(mst + g * 4 + r) * 130 + cn] = ya[ch][f][r] + bb;
        }
    __syncthreads();

    // epilogue: 8 rows per wave — residual + LN (or plain write)
    #pragma unroll
    for (int rr = 0; rr < 8; ++rr) {
        const int row = wv * 8 + rr;
        const size_t t = m0 + row;
        float2 pv = *(float2*)&P[row * 130 + 2 * lane];
        if (DO_LN) {
            float2 hv = ((const float2*)(hf + t * Hh))[lane];
            float a0 = hv.x + pv.x, a1 = hv.y + pv.y;
            float sum = a0 + a1;
            #pragma unroll
            for (int off = 32; off > 0; off >>= 1) sum += __shfl_xor(sum, off);
            const float mean = sum * (1.f / 128.f);
            const float d0 = a0 - mean, d1 = a1 - mean;
            float vs = d0 * d0 + d1 * d1;
            #pragma unroll
            for (int off = 32; off > 0; off >>= 1) vs += __shfl_xor(vs, off);
            const float rstd = rsqrtf(vs * (1.f / 128.f) + 1e-5f);
            float2 gv = ((const float2*)gw)[lane];
            float2 bv = ((const float2*)bw)[lane];
            float2 r = { d0 * rstd * gv.x + bv.x, d1 * rstd * gv.y + bv.y };
            ((float2*)(hf + t * Hh))[lane] = r;
            *(unsigned*)&hb[t * Hh + lane * 2] = pack2_bf16(r.x, r.y);
        } else {
            ((float2*)(hf + t * Hh))[lane] = pv;
            *(unsigned*)&hb[t * Hh + lane * 2] = pack2_bf16(pv.x, pv.y);
        }
    }
}

// ---------------------------------------------------------------------------
// Fused head: [o1|d1] = relu(hb@[out_w1;det_w1]^T + b), logits, sigmoid,
// quality atomics. Block = 32 rows; 192 cols in 3 chunks of 64.
// NO LDS ALIASING: As + Ws + P separate (51.2 KB).
// ---------------------------------------------------------------------------
__global__ __launch_bounds__(256) void head_kernel(
    const short* __restrict__ X,
    const short* __restrict__ W1b, const float* __restrict__ b1,
    const short* __restrict__ DW1b, const float* __restrict__ db1,
    const float* __restrict__ w2, const float* __restrict__ b2,
    const float* __restrict__ dw2, const float* __restrict__ db2,
    float* __restrict__ out)
{
    constexpr int K = 128, ST = K + 8;
    __shared__ short As[32 * ST];
    __shared__ short Ws[64 * ST];
    __shared__ float P[32 * 196];

    const int tid  = threadIdx.x;
    const int lane = tid & 63;
    const int wv   = tid >> 6;
    const int col  = lane & 15;
    const int g    = lane >> 4;
    const int m0   = blockIdx.x * 32;
    const int mst  = (wv & 1) * 16;
    const int cb   = (wv >> 1) * 32;

    for (int i = tid; i < 32 * (K / 8); i += 256) {
        const int r = i / (K / 8), c = (i % (K / 8)) * 8;
        *(bf16x8*)&As[r * ST + c] = *(const bf16x8*)(X + (size_t)(m0 + r) * K + c);
    }

    f32x4 ya[3][2] = {};
    #pragma unroll
    for (int ch = 0; ch < 3; ++ch) {
        for (int i = tid; i < 64 * (K / 8); i += 256) {
            const int r = i / (K / 8), c = (i % (K / 8)) * 8;
            const int rg = ch * 64 + r;
            const short* src = (rg < 128) ? (W1b + (size_t)rg * K)
                                          : (DW1b + (size_t)(rg - 128) * K);
            *(bf16x8*)&Ws[r * ST + c] = *(const bf16x8*)(src + c);
        }
        __syncthreads();
        #pragma unroll
        for (int k0 = 0; k0 < K; k0 += 32) {
            bf16x8 a = *(bf16x8*)&As[(mst + col) * ST + k0 + g * 8];
            #pragma unroll
            for (int f = 0; f < 2; ++f) {
                bf16x8 b = *(bf16x8*)&Ws[(cb + f * 16 + col) * ST + k0 + g * 8];
                ya[ch][f] = __builtin_amdgcn_mfma_f32_16x16x32_bf16(a, b, ya[ch][f], 0, 0, 0);
            }
        }
        __syncthreads();
    }

    #pragma unroll
    for (int ch = 0; ch < 3; ++ch)
        #pragma unroll
        for (int f = 0; f < 2; ++f) {
            const int cn = ch * 64 + cb + f * 16 + col;
            const float bb = (cn < 128) ? b1[cn] : db1[cn - 128];
            #pragma unroll
            for (int r = 0; r < 4; ++r)
                P[(mst + g * 4 + r) * 196 + cn] = fmaxf(ya[ch][f][r] + bb, 0.f);
        }
    __syncthreads();

    const float w20 = w2[2 * lane],       w21 = w2[2 * lane + 1];
    const float w22 = w2[128 + 2 * lane], w23 = w2[129 + 2 * lane];
    const float w24 = w2[256 + 2 * lane], w25 = w2[257 + 2 * lane];
    const float dwl = dw2[lane];
    float qacc = 0.f;
    #pragma unroll
    for (int rr = 0; rr < 8; ++rr) {
        const int row = wv * 8 + rr;
        const size_t t = m0 + row;
        const float x0 = P[row * 196 + 2 * lane];
        const float x1 = P[row * 196 + 2 * lane + 1];
        float s0 = x0 * w20 + x1 * w21;
        float s1 = x0 * w22 + x1 * w23;
        float s2 = x0 * w24 + x1 * w25;
        float d  = P[row * 196 + 128 + lane] * dwl;
        #pragma unroll
        for (int off = 32; off > 0; off >>= 1) {
            s0 += __shfl_xor(s0, off);
            s1 += __shfl_xor(s1, off);
            s2 += __shfl_xor(s2, off);
            d  += __shfl_xor(d,  off);
        }
        if (lane == 0) {
            out[t * 3 + 0] = s0 + b2[0];
            out[t * 3 + 1] = s1 + b2[1];
            out[t * 3 + 2] = s2 + b2[2];
            const float prob = 1.f / (1.f + __expf(-(d + db2[0])));
            out[24576 + t] = prob;
            qacc += prob;
        }
    }
    if (lane == 0)
        atomicAdd(&out[32768 + (m0 >> 11)], qacc * (1.f / (float)Nn));
}

// ---------------------------------------------------------------------------
// MFMA flash attention — byte-identical to R6 (verified)
// ---------------------------------------------------------------------------
constexpr int KT = 128;
constexpr int KS = 28;
constexpr int VS = 132;

__global__ __launch_bounds__(256) void attn_kernel(
    const short* __restrict__ qkv, short* __restrict__ out)
{
    __shared__ short Ks[KT * KS];
    __shared__ short Vs[DHh * VS];

    const int tid  = threadIdx.x;
    const int lane = tid & 63;
    const int wv   = tid >> 6;
    const int col  = lane & 15;
    const int g    = lane >> 4;
    const int hd   = blockIdx.y;
    const int b    = blockIdx.z;
    const int q0   = blockIdx.x * 64 + wv * 16;

    const short* base = qkv + (size_t)b * Nn * 384;

    bf16x8 qf = {};
    if (g < 2) {
        bf16x8 qraw = *(const bf16x8*)(base + (size_t)(q0 + col) * 384 + hd * DHh + g * 8);
        const float qs = 0.25f * LOG2E;
        #pragma unroll
        for (int i = 0; i < 8; ++i)
            qf[i] = f32_to_bf16_rne(bf16_to_f32(qraw[i]) * qs);
    }

    float m = -1e30f, lsum = 0.f;
    f32x4 o = {0.f, 0.f, 0.f, 0.f};

    const int ksr = tid >> 1;
    const int ksd = (tid & 1) * 8;
    const int va  = tid >> 2;
    const int vd  = (tid & 3) * 4;

    for (int kt = 0; kt < Nn; kt += KT) {
        __syncthreads();
        {
            *(bf16x8*)&Ks[ksr * KS + ksd] =
                *(const bf16x8*)(base + (size_t)(kt + ksr) * 384 + Hh + hd * DHh + ksd);
            const short* v0 = base + (size_t)(kt + 2 * va) * 384 + 2 * Hh + hd * DHh + vd;
            bf16x4 r0 = *(const bf16x4*)v0;
            bf16x4 r1 = *(const bf16x4*)(v0 + 384);
            unsigned a0 = ((const unsigned*)&r0)[0], a1 = ((const unsigned*)&r0)[1];
            unsigned b0 = ((const unsigned*)&r1)[0], b1 = ((const unsigned*)&r1)[1];
            *(unsigned*)&Vs[(vd + 0) * VS + 2 * va] = __builtin_amdgcn_perm(b0, a0, 0x05040100);
            *(unsigned*)&Vs[(vd + 1) * VS + 2 * va] = __builtin_amdgcn_perm(b0, a0, 0x07060302);
            *(unsigned*)&Vs[(vd + 2) * VS + 2 * va] = __builtin_amdgcn_perm(b1, a1, 0x05040100);
            *(unsigned*)&Vs[(vd + 3) * VS + 2 * va] = __builtin_amdgcn_perm(b1, a1, 0x07060302);
        }
        __syncthreads();

        f32x4 scr[8];
        #pragma unroll
        for (int s = 0; s < 4; ++s) {
            bf16x8 kf0 = {}, kf1 = {};
            if (g < 2) {
                kf0 = *(bf16x8*)&Ks[(s * 32 + col) * KS + g * 8];
                kf1 = *(bf16x8*)&Ks[(s * 32 + 16 + col) * KS + g * 8];
            }
            f32x4 z = {0.f, 0.f, 0.f, 0.f};
            scr[2 * s]     = __builtin_amdgcn_mfma_f32_16x16x32_bf16(kf0, qf, z, 0, 0, 0);
            scr[2 * s + 1] = __builtin_amdgcn_mfma_f32_16x16x32_bf16(kf1, qf, z, 0, 0, 0);
        }

        float tmax = scr[0][0];
        #pragma unroll
        for (int i = 0; i < 8; ++i)
            #pragma unroll
            for (int r = 0; r < 4; ++r) tmax = fmaxf(tmax, scr[i][r]);
        tmax = fmaxf(tmax, __shfl_xor(tmax, 16));
        tmax = fmaxf(tmax, __shfl_xor(tmax, 32));
        const float mnew  = fmaxf(m, tmax);
        const float alpha = exp2f(m - mnew);
        m = mnew;
        lsum *= alpha;
        #pragma unroll
        for (int r = 0; r < 4; ++r)
            o[r] *= __shfl(alpha, g * 4 + r);

        #pragma unroll
        for (int s = 0; s < 4; ++s) {
            float pA[4], pB[4];
            #pragma unroll
            for (int r = 0; r < 4; ++r) {
                pA[r] = exp2f(scr[2 * s][r] - mnew);
                pB[r] = exp2f(scr[2 * s + 1][r] - mnew);
            }
            lsum += ((pA[0] + pA[1]) + (pA[2] + pA[3]))
                  + ((pB[0] + pB[1]) + (pB[2] + pB[3]));

            union { bf16x8 v; unsigned u[4]; } pf;
            pf.u[0] = pack2_bf16(pA[0], pA[1]);
            pf.u[1] = pack2_bf16(pA[2], pA[3]);
            pf.u[2] = pack2_bf16(pB[0], pB[1]);
            pf.u[3] = pack2_bf16(pB[2], pB[3]);

            bf16x8 vf;
            ((bf16x4*)&vf)[0] = *(bf16x4*)&Vs[col * VS + s * 32 + g * 4];
            ((bf16x4*)&vf)[1] = *(bf16x4*)&Vs[col * VS + s * 32 + 16 + g * 4];

            o = __builtin_amdgcn_mfma_f32_16x16x32_bf16(pf.v, vf, o, 0, 0, 0);
        }
    }

    float lt = lsum;
    lt += __shfl_xor(lt, 16);
    lt += __shfl_xor(lt, 32);
    const float inv = 1.f / lt;

    #pragma unroll
    for (int r = 0; r < 4; ++r) {
        const float invr = __shfl(inv, g * 4 + r);
        out[(size_t)(b * Nn + q0 + g * 4 + r) * Hh + hd * DHh + col] =
            f32_to_bf16_rne(o[r] * invr);
    }
}

// ---------------------------------------------------------------------------
extern "C" void kernel_launch(void* const* d_in, const int* in_sizes, int n_in,
                              void* d_out, int out_size, void* d_ws, size_t ws_size,
                              hipStream_t stream)
{
    char* W8 = (char*)d_ws;
    float* hf   = (float*)(W8 + 0);            // 4MB  fp32 residual spine
    short* hb   = (short*)(W8 + 4194304);      // 2MB  bf16 mirror
    short* wb   = (short*)(W8 + 6291456);      // 1MB  bf16 weights
    char*  regA = W8 + 7340032;                // 6MB  xb / qkvb / ub
    char*  regB = W8 + 13631488;               // 2MB  t1b / attno

    short* xb    = (short*)regA;               // [8192,256]
    short* qkvb  = (short*)regA;               // [8192,384]
    short* ub    = (short*)regA;               // [8192,256]
    short* t1b   = (short*)regB;               // [8192,128]
    short* attno = (short*)regB;               // [8192,128]
    float* out   = (float*)d_out;

    const int wsz[12]  = {32768,16384,49152,16384,32768,32768,49152,16384,32768,32768,16384,8192};
    const int wsrc[12] = {1, 3, 5, 7, 9, 11, 17, 19, 21, 23, 29, 33};
    int woff[13]; woff[0] = 0;
    for (int i = 0; i < 12; ++i) woff[i + 1] = woff[i] + wsz[i];

    CvtJobs jobs;
    int acc = 0;
    for (int i = 0; i < 12; ++i) {
        jobs.src[i] = (const float*)d_in[wsrc[i]];
        jobs.dst[i] = wb + woff[i];
        jobs.off[i] = acc;
        acc += wsz[i] / 4;
    }
    jobs.src[12] = (const float*)d_in[0];
    jobs.dst[12] = xb;
    jobs.off[12] = acc;
    acc += (MTOK * Cc) / 4;
    jobs.off[13] = acc;
    jobs.qzero = out + 32768;

    hipLaunchKernelGGL(cvt_kernel, dim3((acc + 255) / 256), dim3(256), 0, stream, jobs);

    auto gemm = [&](const short* X, const short* Wgt, const float* bias,
                    short* Yb, int M, int N, int K, int relu) {
        hipLaunchKernelGGL(gemm_bf16_kernel, dim3(N / 64, M / 64), dim3(256), 0, stream,
                           X, Wgt, bias, Yb, M, N, K, relu);
    };

    // feature fusion: t1 = relu(x@fw1^T+b1); h = t1@fw2^T+b2 (no LN)
    gemm(xb, wb + woff[0], (const float*)d_in[2], t1b, MTOK, Hh, Cc, 1);
    hipLaunchKernelGGL((gemmln_kernel<128, 64, false>), dim3(MTOK / 32), dim3(256), 0, stream,
                       t1b, wb + woff[1], (const float*)d_in[4], hf, hb, nullptr, nullptr);

    for (int l = 0; l < 2; ++l) {
        const int ib = 5 + l * 12;
        const int wbase = 2 + l * 4;
        gemm(hb, wb + woff[wbase + 0], (const float*)d_in[ib + 1], qkvb, MTOK, 3 * Hh, Hh, 0);
        hipLaunchKernelGGL(attn_kernel, dim3(Nn / 64, NHh, Bb), dim3(256), 0, stream,
                           qkvb, attno);
        hipLaunchKernelGGL((gemmln_kernel<128, 64, true>), dim3(MTOK / 32), dim3(256), 0, stream,
                           attno, wb + woff[wbase + 1], (const float*)d_in[ib + 3],
                           hf, hb, (const float*)d_in[ib + 8], (const float*)d_in[ib + 9]);
        gemm(hb, wb + woff[wbase + 2], (const float*)d_in[ib + 5], ub, MTOK, 2 * Hh, Hh, 1);
        hipLaunchKernelGGL((gemmln_kernel<256, 32, true>), dim3(MTOK / 32), dim3(256), 0, stream,
                           ub, wb + woff[wbase + 3], (const float*)d_in[ib + 7],
                           hf, hb, (const float*)d_in[ib + 10], (const float*)d_in[ib + 11]);
    }

    hipLaunchKernelGGL(head_kernel, dim3(MTOK / 32), dim3(256), 0, stream,
                       hb, wb + woff[10], (const float*)d_in[30],
                       wb + woff[11], (const float*)d_in[34],
                       (const float*)d_in[31], (const float*)d_in[32],
                       (const float*)d_in[35], (const float*)d_in[36], out);
}

// Round 9
// 308.723 us; speedup vs baseline: 12.5915x; 1.1394x over previous
//
#include <hip/hip_runtime.h>
#include <cstddef>

constexpr int Bb  = 4;
constexpr int Nn  = 2048;
constexpr int Cc  = 256;
constexpr int Hh  = 128;
constexpr int NHh = 8;
constexpr int DHh = 16;
constexpr int MTOK = Bb * Nn;           // 8192 tokens
#define LOG2E 1.4426950408889634f

typedef __attribute__((ext_vector_type(8))) short bf16x8;
typedef __attribute__((ext_vector_type(4))) short bf16x4;
typedef __attribute__((ext_vector_type(4))) float f32x4;

__device__ __forceinline__ short f32_to_bf16_rne(float f) {
    union { float f; unsigned int u; } c; c.f = f;
    unsigned int r = c.u + 0x7fffu + ((c.u >> 16) & 1u);
    return (short)(r >> 16);
}
__device__ __forceinline__ float bf16_to_f32(short s) {
    union { float f; unsigned int u; } c; c.u = ((unsigned int)(unsigned short)s) << 16;
    return c.f;
}
__device__ __forceinline__ unsigned pack2_bf16(float a, float b) {
    unsigned ua = __float_as_uint(a);
    unsigned ub = __float_as_uint(b);
    ua += 0x7fffu + ((ua >> 16) & 1u);
    ub += 0x7fffu + ((ub >> 16) & 1u);
    return __builtin_amdgcn_perm(ub, ua, 0x07060302);
}

// ---------------------------------------------------------------------------
// fp32 -> bf16 conversion (weights + x) + zero the 4 quality accumulators
// ---------------------------------------------------------------------------
struct CvtJobs {
    const float* src[13];
    short*       dst[13];
    int          off[14];
    float*       qzero;
};

__global__ __launch_bounds__(256) void cvt_kernel(CvtJobs j) {
    const int gid = blockIdx.x * 256 + threadIdx.x;
    if (blockIdx.x == 0 && threadIdx.x < 4) j.qzero[threadIdx.x] = 0.f;
    if (gid >= j.off[13]) return;
    int k = 0;
    #pragma unroll
    for (int i = 0; i < 12; ++i) if (gid >= j.off[i + 1]) k = i + 1;
    const int idx = (gid - j.off[k]) * 4;
    float4 v = *(const float4*)(j.src[k] + idx);
    short o4[4] = { f32_to_bf16_rne(v.x), f32_to_bf16_rne(v.y),
                    f32_to_bf16_rne(v.z), f32_to_bf16_rne(v.w) };
    *(bf16x4*)(j.dst[k] + idx) = *(bf16x4*)o4;
}

// ---------------------------------------------------------------------------
// Plain bf16 MFMA GEMM (R3/R6-verified): 64x64 tile, BK=32, 4 waves.
// ---------------------------------------------------------------------------
__global__ __launch_bounds__(256) void gemm_bf16_kernel(
    const short* __restrict__ X, const short* __restrict__ W,
    const float* __restrict__ bias, short* __restrict__ Yb,
    int M, int N, int K, int relu)
{
    __shared__ short As[64 * 40];
    __shared__ short Bs[64 * 40];

    const int tid  = threadIdx.x;
    const int lane = tid & 63;
    const int wv   = tid >> 6;
    const int col  = lane & 15;
    const int g    = lane >> 4;
    const int m0   = blockIdx.y * 64;
    const int n0   = blockIdx.x * 64;
    const int sr   = tid >> 2;
    const int sc   = (tid & 3) * 8;

    f32x4 acc[4] = {};

    for (int k0 = 0; k0 < K; k0 += 32) {
        __syncthreads();
        *(bf16x8*)&As[sr * 40 + sc] =
            *(const bf16x8*)(X + (size_t)(m0 + sr) * K + k0 + sc);
        *(bf16x8*)&Bs[sr * 40 + sc] =
            *(const bf16x8*)(W + (size_t)(n0 + sr) * K + k0 + sc);
        __syncthreads();

        bf16x8 a = *(bf16x8*)&As[(wv * 16 + col) * 40 + g * 8];
        #pragma unroll
        for (int jj = 0; jj < 4; ++jj) {
            bf16x8 b = *(bf16x8*)&Bs[(jj * 16 + col) * 40 + g * 8];
            acc[jj] = __builtin_amdgcn_mfma_f32_16x16x32_bf16(a, b, acc[jj], 0, 0, 0);
        }
    }

    #pragma unroll
    for (int jj = 0; jj < 4; ++jj) {
        const int cn = n0 + jj * 16 + col;
        const float bb = bias[cn];
        #pragma unroll
        for (int r = 0; r < 4; ++r) {
            const int rm = m0 + wv * 16 + g * 4 + r;
            float v = acc[jj][r] + bb;
            if (relu) v = fmaxf(v, 0.f);
            Yb[(size_t)rm * N + cn] = f32_to_bf16_rne(v);
        }
    }
}

// ---------------------------------------------------------------------------
// Fused GEMM(+bias) + residual + LayerNorm (R7-verified, no LDS aliasing)
// ---------------------------------------------------------------------------
template<int K, int CR, bool DO_LN>
__global__ __launch_bounds__(256) void gemmln_kernel(
    const short* __restrict__ X, const short* __restrict__ W,
    const float* __restrict__ bias,
    float* __restrict__ hf, short* __restrict__ hb,
    const float* __restrict__ gw, const float* __restrict__ bw)
{
    constexpr int ST  = K + 8;
    constexpr int NCH = 128 / CR;
    constexpr int NF  = CR / 32;
    __shared__ short As[32 * ST];
    __shared__ short Ws[CR * ST];
    __shared__ float P[32 * 130];

    const int tid  = threadIdx.x;
    const int lane = tid & 63;
    const int wv   = tid >> 6;
    const int col  = lane & 15;
    const int g    = lane >> 4;
    const int m0   = blockIdx.x * 32;
    const int mst  = (wv & 1) * 16;
    const int cb   = (wv >> 1) * (CR / 2);

    for (int i = tid; i < 32 * (K / 8); i += 256) {
        const int r = i / (K / 8), c = (i % (K / 8)) * 8;
        *(bf16x8*)&As[r * ST + c] = *(const bf16x8*)(X + (size_t)(m0 + r) * K + c);
    }

    f32x4 ya[NCH][NF] = {};
    #pragma unroll
    for (int ch = 0; ch < NCH; ++ch) {
        for (int i = tid; i < CR * (K / 8); i += 256) {
            const int r = i / (K / 8), c = (i % (K / 8)) * 8;
            *(bf16x8*)&Ws[r * ST + c] =
                *(const bf16x8*)(W + (size_t)(ch * CR + r) * K + c);
        }
        __syncthreads();
        #pragma unroll
        for (int k0 = 0; k0 < K; k0 += 32) {
            bf16x8 a = *(bf16x8*)&As[(mst + col) * ST + k0 + g * 8];
            #pragma unroll
            for (int f = 0; f < NF; ++f) {
                bf16x8 b = *(bf16x8*)&Ws[(cb + f * 16 + col) * ST + k0 + g * 8];
                ya[ch][f] = __builtin_amdgcn_mfma_f32_16x16x32_bf16(a, b, ya[ch][f], 0, 0, 0);
            }
        }
        __syncthreads();
    }

    #pragma unroll
    for (int ch = 0; ch < NCH; ++ch)
        #pragma unroll
        for (int f = 0; f < NF; ++f) {
            const int cn = ch * CR + cb + f * 16 + col;
            const float bb = bias[cn];
            #pragma unroll
            for (int r = 0; r < 4; ++r)
                P[(mst + g * 4 + r) * 130 + cn] = ya[ch][f][r] + bb;
        }
    __syncthreads();

    #pragma unroll
    for (int rr = 0; rr < 8; ++rr) {
        const int row = wv * 8 + rr;
        const size_t t = m0 + row;
        float2 pv = *(float2*)&P[row * 130 + 2 * lane];
        if (DO_LN) {
            float2 hv = ((const float2*)(hf + t * Hh))[lane];
            float a0 = hv.x + pv.x, a1 = hv.y + pv.y;
            float sum = a0 + a1;
            #pragma unroll
            for (int off = 32; off > 0; off >>= 1) sum += __shfl_xor(sum, off);
            const float mean = sum * (1.f / 128.f);
            const float d0 = a0 - mean, d1 = a1 - mean;
            float vs = d0 * d0 + d1 * d1;
            #pragma unroll
            for (int off = 32; off > 0; off >>= 1) vs += __shfl_xor(vs, off);
            const float rstd = rsqrtf(vs * (1.f / 128.f) + 1e-5f);
            float2 gv = ((const float2*)gw)[lane];
            float2 bv = ((const float2*)bw)[lane];
            float2 r = { d0 * rstd * gv.x + bv.x, d1 * rstd * gv.y + bv.y };
            ((float2*)(hf + t * Hh))[lane] = r;
            *(unsigned*)&hb[t * Hh + lane * 2] = pack2_bf16(r.x, r.y);
        } else {
            ((float2*)(hf + t * Hh))[lane] = pv;
            *(unsigned*)&hb[t * Hh + lane * 2] = pack2_bf16(pv.x, pv.y);
        }
    }
}

// ---------------------------------------------------------------------------
// Fused head (R7-verified, no LDS aliasing)
// ---------------------------------------------------------------------------
__global__ __launch_bounds__(256) void head_kernel(
    const short* __restrict__ X,
    const short* __restrict__ W1b, const float* __restrict__ b1,
    const short* __restrict__ DW1b, const float* __restrict__ db1,
    const float* __restrict__ w2, const float* __restrict__ b2,
    const float* __restrict__ dw2, const float* __restrict__ db2,
    float* __restrict__ out)
{
    constexpr int K = 128, ST = K + 8;
    __shared__ short As[32 * ST];
    __shared__ short Ws[64 * ST];
    __shared__ float P[32 * 196];

    const int tid  = threadIdx.x;
    const int lane = tid & 63;
    const int wv   = tid >> 6;
    const int col  = lane & 15;
    const int g    = lane >> 4;
    const int m0   = blockIdx.x * 32;
    const int mst  = (wv & 1) * 16;
    const int cb   = (wv >> 1) * 32;

    for (int i = tid; i < 32 * (K / 8); i += 256) {
        const int r = i / (K / 8), c = (i % (K / 8)) * 8;
        *(bf16x8*)&As[r * ST + c] = *(const bf16x8*)(X + (size_t)(m0 + r) * K + c);
    }

    f32x4 ya[3][2] = {};
    #pragma unroll
    for (int ch = 0; ch < 3; ++ch) {
        for (int i = tid; i < 64 * (K / 8); i += 256) {
            const int r = i / (K / 8), c = (i % (K / 8)) * 8;
            const int rg = ch * 64 + r;
            const short* src = (rg < 128) ? (W1b + (size_t)rg * K)
                                          : (DW1b + (size_t)(rg - 128) * K);
            *(bf16x8*)&Ws[r * ST + c] = *(const bf16x8*)(src + c);
        }
        __syncthreads();
        #pragma unroll
        for (int k0 = 0; k0 < K; k0 += 32) {
            bf16x8 a = *(bf16x8*)&As[(mst + col) * ST + k0 + g * 8];
            #pragma unroll
            for (int f = 0; f < 2; ++f) {
                bf16x8 b = *(bf16x8*)&Ws[(cb + f * 16 + col) * ST + k0 + g * 8];
                ya[ch][f] = __builtin_amdgcn_mfma_f32_16x16x32_bf16(a, b, ya[ch][f], 0, 0, 0);
            }
        }
        __syncthreads();
    }

    #pragma unroll
    for (int ch = 0; ch < 3; ++ch)
        #pragma unroll
        for (int f = 0; f < 2; ++f) {
            const int cn = ch * 64 + cb + f * 16 + col;
            const float bb = (cn < 128) ? b1[cn] : db1[cn - 128];
            #pragma unroll
            for (int r = 0; r < 4; ++r)
                P[(mst + g * 4 + r) * 196 + cn] = fmaxf(ya[ch][f][r] + bb, 0.f);
        }
    __syncthreads();

    const float w20 = w2[2 * lane],       w21 = w2[2 * lane + 1];
    const float w22 = w2[128 + 2 * lane], w23 = w2[129 + 2 * lane];
    const float w24 = w2[256 + 2 * lane], w25 = w2[257 + 2 * lane];
    const float dwl = dw2[lane];
    float qacc = 0.f;
    #pragma unroll
    for (int rr = 0; rr < 8; ++rr) {
        const int row = wv * 8 + rr;
        const size_t t = m0 + row;
        const float x0 = P[row * 196 + 2 * lane];
        const float x1 = P[row * 196 + 2 * lane + 1];
        float s0 = x0 * w20 + x1 * w21;
        float s1 = x0 * w22 + x1 * w23;
        float s2 = x0 * w24 + x1 * w25;
        float d  = P[row * 196 + 128 + lane] * dwl;
        #pragma unroll
        for (int off = 32; off > 0; off >>= 1) {
            s0 += __shfl_xor(s0, off);
            s1 += __shfl_xor(s1, off);
            s2 += __shfl_xor(s2, off);
            d  += __shfl_xor(d,  off);
        }
        if (lane == 0) {
            out[t * 3 + 0] = s0 + b2[0];
            out[t * 3 + 1] = s1 + b2[1];
            out[t * 3 + 2] = s2 + b2[2];
            const float prob = 1.f / (1.f + __expf(-(d + db2[0])));
            out[24576 + t] = prob;
            qacc += prob;
        }
    }
    if (lane == 0)
        atomicAdd(&out[32768 + (m0 >> 11)], qacc * (1.f / (float)Nn));
}

// ---------------------------------------------------------------------------
// MFMA flash attention, bf16 qkv. NEW this round: no-max softmax (scores are
// small by construction — shift-invariant, fp32 exp2 safe to |s|>100) and
// row-sum via a ones-B MFMA on the idle matrix pipe. Single pass per 32-key
// group: 2 S-MFMAs -> exp2 -> pack -> PV-MFMA + ones-MFMA. No cross-lane ops.
// Final: out = o[r] * rcp(lacc[r]) — layouts match exactly.
// ---------------------------------------------------------------------------
constexpr int KT = 128;
constexpr int KS = 28;     // bf16 per K row (16 padded to 28)
constexpr int VS = 132;    // bf16 per V^T row (128 padded to 132)

__global__ __launch_bounds__(256) void attn_kernel(
    const short* __restrict__ qkv, short* __restrict__ out)
{
    __shared__ short Ks[KT * KS];   // [key][dim]
    __shared__ short Vs[DHh * VS];  // [dim][key]

    const int tid  = threadIdx.x;
    const int lane = tid & 63;
    const int wv   = tid >> 6;
    const int col  = lane & 15;
    const int g    = lane >> 4;
    const int hd   = blockIdx.y;
    const int b    = blockIdx.z;
    const int q0   = blockIdx.x * 64 + wv * 16;

    const short* base = qkv + (size_t)b * Nn * 384;

    // Q fragment (B operand of S), pre-scaled by 1/sqrt(DH)*log2(e)
    bf16x8 qf = {};
    if (g < 2) {
        bf16x8 qraw = *(const bf16x8*)(base + (size_t)(q0 + col) * 384 + hd * DHh + g * 8);
        const float qs = 0.25f * LOG2E;
        #pragma unroll
        for (int i = 0; i < 8; ++i)
            qf[i] = f32_to_bf16_rne(bf16_to_f32(qraw[i]) * qs);
    }

    f32x4 o    = {0.f, 0.f, 0.f, 0.f};     // O[q=g*4+r][d=col] (unnormalized)
    f32x4 lacc = {0.f, 0.f, 0.f, 0.f};     // lsum[q=g*4+r], same layout
    const short one_bf16 = (short)0x3F80;
    const bf16x8 ones = { one_bf16, one_bf16, one_bf16, one_bf16,
                          one_bf16, one_bf16, one_bf16, one_bf16 };

    const int ksr = tid >> 1;              // key 0..127
    const int ksd = (tid & 1) * 8;         // dim half
    const int va  = tid >> 2;              // key pair 2*va
    const int vd  = (tid & 3) * 4;         // dims vd..vd+3

    for (int kt = 0; kt < Nn; kt += KT) {
        __syncthreads();
        {
            *(bf16x8*)&Ks[ksr * KS + ksd] =
                *(const bf16x8*)(base + (size_t)(kt + ksr) * 384 + Hh + hd * DHh + ksd);
            const short* v0 = base + (size_t)(kt + 2 * va) * 384 + 2 * Hh + hd * DHh + vd;
            bf16x4 r0 = *(const bf16x4*)v0;
            bf16x4 r1 = *(const bf16x4*)(v0 + 384);
            unsigned a0 = ((const unsigned*)&r0)[0], a1 = ((const unsigned*)&r0)[1];
            unsigned b0 = ((const unsigned*)&r1)[0], b1 = ((const unsigned*)&r1)[1];
            *(unsigned*)&Vs[(vd + 0) * VS + 2 * va] = __builtin_amdgcn_perm(b0, a0, 0x05040100);
            *(unsigned*)&Vs[(vd + 1) * VS + 2 * va] = __builtin_amdgcn_perm(b0, a0, 0x07060302);
            *(unsigned*)&Vs[(vd + 2) * VS + 2 * va] = __builtin_amdgcn_perm(b1, a1, 0x05040100);
            *(unsigned*)&Vs[(vd + 3) * VS + 2 * va] = __builtin_amdgcn_perm(b1, a1, 0x07060302);
        }
        __syncthreads();

        #pragma unroll
        for (int s = 0; s < 4; ++s) {
            bf16x8 kf0 = {}, kf1 = {};
            if (g < 2) {
                kf0 = *(bf16x8*)&Ks[(s * 32 + col) * KS + g * 8];
                kf1 = *(bf16x8*)&Ks[(s * 32 + 16 + col) * KS + g * 8];
            }
            f32x4 z = {0.f, 0.f, 0.f, 0.f};
            f32x4 sA = __builtin_amdgcn_mfma_f32_16x16x32_bf16(kf0, qf, z, 0, 0, 0);
            f32x4 sB = __builtin_amdgcn_mfma_f32_16x16x32_bf16(kf1, qf, z, 0, 0, 0);
            // sA[r]=S_log2[key s*32+g*4+r][q=col]; sB: +16 keys

            // p = exp2(s) directly (no max shift), pack to A-operand slots
            union { bf16x8 v; unsigned u[4]; } pf;
            pf.u[0] = pack2_bf16(__builtin_amdgcn_exp2f(sA[0]),
                                 __builtin_amdgcn_exp2f(sA[1]));
            pf.u[1] = pack2_bf16(__builtin_amdgcn_exp2f(sA[2]),
                                 __builtin_amdgcn_exp2f(sA[3]));
            pf.u[2] = pack2_bf16(__builtin_amdgcn_exp2f(sB[0]),
                                 __builtin_amdgcn_exp2f(sB[1]));
            pf.u[3] = pack2_bf16(__builtin_amdgcn_exp2f(sB[2]),
                                 __builtin_amdgcn_exp2f(sB[3]));

            bf16x8 vf;
            ((bf16x4*)&vf)[0] = *(bf16x4*)&Vs[col * VS + s * 32 + g * 4];
            ((bf16x4*)&vf)[1] = *(bf16x4*)&Vs[col * VS + s * 32 + 16 + g * 4];

            o    = __builtin_amdgcn_mfma_f32_16x16x32_bf16(pf.v, vf,   o,    0, 0, 0);
            lacc = __builtin_amdgcn_mfma_f32_16x16x32_bf16(pf.v, ones, lacc, 0, 0, 0);
        }
    }

    #pragma unroll
    for (int r = 0; r < 4; ++r) {
        const float inv = __builtin_amdgcn_rcpf(lacc[r]);
        out[(size_t)(b * Nn + q0 + g * 4 + r) * Hh + hd * DHh + col] =
            f32_to_bf16_rne(o[r] * inv);
    }
}

// ---------------------------------------------------------------------------
extern "C" void kernel_launch(void* const* d_in, const int* in_sizes, int n_in,
                              void* d_out, int out_size, void* d_ws, size_t ws_size,
                              hipStream_t stream)
{
    char* W8 = (char*)d_ws;
    float* hf   = (float*)(W8 + 0);            // 4MB  fp32 residual spine
    short* hb   = (short*)(W8 + 4194304);      // 2MB  bf16 mirror
    short* wb   = (short*)(W8 + 6291456);      // 1MB  bf16 weights
    char*  regA = W8 + 7340032;                // 6MB  xb / qkvb / ub
    char*  regB = W8 + 13631488;               // 2MB  t1b / attno

    short* xb    = (short*)regA;               // [8192,256]
    short* qkvb  = (short*)regA;               // [8192,384]
    short* ub    = (short*)regA;               // [8192,256]
    short* t1b   = (short*)regB;               // [8192,128]
    short* attno = (short*)regB;               // [8192,128]
    float* out   = (float*)d_out;

    const int wsz[12]  = {32768,16384,49152,16384,32768,32768,49152,16384,32768,32768,16384,8192};
    const int wsrc[12] = {1, 3, 5, 7, 9, 11, 17, 19, 21, 23, 29, 33};
    int woff[13]; woff[0] = 0;
    for (int i = 0; i < 12; ++i) woff[i + 1] = woff[i] + wsz[i];

    CvtJobs jobs;
    int acc = 0;
    for (int i = 0; i < 12; ++i) {
        jobs.src[i] = (const float*)d_in[wsrc[i]];
        jobs.dst[i] = wb + woff[i];
        jobs.off[i] = acc;
        acc += wsz[i] / 4;
    }
    jobs.src[12] = (const float*)d_in[0];
    jobs.dst[12] = xb;
    jobs.off[12] = acc;
    acc += (MTOK * Cc) / 4;
    jobs.off[13] = acc;
    jobs.qzero = out + 32768;

    hipLaunchKernelGGL(cvt_kernel, dim3((acc + 255) / 256), dim3(256), 0, stream, jobs);

    auto gemm = [&](const short* X, const short* Wgt, const float* bias,
                    short* Yb, int M, int N, int K, int relu) {
        hipLaunchKernelGGL(gemm_bf16_kernel, dim3(N / 64, M / 64), dim3(256), 0, stream,
                           X, Wgt, bias, Yb, M, N, K, relu);
    };

    // feature fusion: t1 = relu(x@fw1^T+b1); h = t1@fw2^T+b2 (no LN)
    gemm(xb, wb + woff[0], (const float*)d_in[2], t1b, MTOK, Hh, Cc, 1);
    hipLaunchKernelGGL((gemmln_kernel<128, 64, false>), dim3(MTOK / 32), dim3(256), 0, stream,
                       t1b, wb + woff[1], (const float*)d_in[4], hf, hb, nullptr, nullptr);

    for (int l = 0; l < 2; ++l) {
        const int ib = 5 + l * 12;
        const int wbase = 2 + l * 4;
        gemm(hb, wb + woff[wbase + 0], (const float*)d_in[ib + 1], qkvb, MTOK, 3 * Hh, Hh, 0);
        hipLaunchKernelGGL(attn_kernel, dim3(Nn / 64, NHh, Bb), dim3(256), 0, stream,
                           qkvb, attno);
        hipLaunchKernelGGL((gemmln_kernel<128, 64, true>), dim3(MTOK / 32), dim3(256), 0, stream,
                           attno, wb + woff[wbase + 1], (const float*)d_in[ib + 3],
                           hf, hb, (const float*)d_in[ib + 8], (const float*)d_in[ib + 9]);
        gemm(hb, wb + woff[wbase + 2], (const float*)d_in[ib + 5], ub, MTOK, 2 * Hh, Hh, 1);
        hipLaunchKernelGGL((gemmln_kernel<256, 32, true>), dim3(MTOK / 32), dim3(256), 0, stream,
                           ub, wb + woff[wbase + 3], (const float*)d_in[ib + 7],
                           hf, hb, (const float*)d_in[ib + 10], (const float*)d_in[ib + 11]);
    }

    hipLaunchKernelGGL(head_kernel, dim3(MTOK / 32), dim3(256), 0, stream,
                       hb, wb + woff[10], (const float*)d_in[30],
                       wb + woff[11], (const float*)d_in[34],
                       (const float*)d_in[31], (const float*)d_in[32],
                       (const float*)d_in[35], (const float*)d_in[36], out);
}

// Round 10
// 299.066 us; speedup vs baseline: 12.9981x; 1.0323x over previous
//
#include <hip/hip_runtime.h>
#include <cstddef>

constexpr int Bb  = 4;
constexpr int Nn  = 2048;
constexpr int Cc  = 256;
constexpr int Hh  = 128;
constexpr int NHh = 8;
constexpr int DHh = 16;
constexpr int MTOK = Bb * Nn;           // 8192 tokens
#define LOG2E 1.4426950408889634f

typedef __attribute__((ext_vector_type(8))) short bf16x8;
typedef __attribute__((ext_vector_type(4))) short bf16x4;
typedef __attribute__((ext_vector_type(4))) float f32x4;

__device__ __forceinline__ short f32_to_bf16_rne(float f) {
    union { float f; unsigned int u; } c; c.f = f;
    unsigned int r = c.u + 0x7fffu + ((c.u >> 16) & 1u);
    return (short)(r >> 16);
}
__device__ __forceinline__ float bf16_to_f32(short s) {
    union { float f; unsigned int u; } c; c.u = ((unsigned int)(unsigned short)s) << 16;
    return c.f;
}
__device__ __forceinline__ unsigned pack2_bf16(float a, float b) {
    unsigned ua = __float_as_uint(a);
    unsigned ub = __float_as_uint(b);
    ua += 0x7fffu + ((ua >> 16) & 1u);
    ub += 0x7fffu + ((ub >> 16) & 1u);
    return __builtin_amdgcn_perm(ub, ua, 0x07060302);
}

// ---------------------------------------------------------------------------
// fp32 -> bf16 conversion (weights + x) + zero the 4 quality accumulators
// ---------------------------------------------------------------------------
struct CvtJobs {
    const float* src[13];
    short*       dst[13];
    int          off[14];
    float*       qzero;
};

__global__ __launch_bounds__(256) void cvt_kernel(CvtJobs j) {
    const int gid = blockIdx.x * 256 + threadIdx.x;
    if (blockIdx.x == 0 && threadIdx.x < 4) j.qzero[threadIdx.x] = 0.f;
    if (gid >= j.off[13]) return;
    int k = 0;
    #pragma unroll
    for (int i = 0; i < 12; ++i) if (gid >= j.off[i + 1]) k = i + 1;
    const int idx = (gid - j.off[k]) * 4;
    float4 v = *(const float4*)(j.src[k] + idx);
    short o4[4] = { f32_to_bf16_rne(v.x), f32_to_bf16_rne(v.y),
                    f32_to_bf16_rne(v.z), f32_to_bf16_rne(v.w) };
    *(bf16x4*)(j.dst[k] + idx) = *(bf16x4*)o4;
}

// ---------------------------------------------------------------------------
// Plain bf16 MFMA GEMM (R3/R6-verified): 64x64 tile, BK=32, 4 waves.
// Used only for the qkv projection now.
// ---------------------------------------------------------------------------
__global__ __launch_bounds__(256) void gemm_bf16_kernel(
    const short* __restrict__ X, const short* __restrict__ W,
    const float* __restrict__ bias, short* __restrict__ Yb,
    int M, int N, int K, int relu)
{
    __shared__ short As[64 * 40];
    __shared__ short Bs[64 * 40];

    const int tid  = threadIdx.x;
    const int lane = tid & 63;
    const int wv   = tid >> 6;
    const int col  = lane & 15;
    const int g    = lane >> 4;
    const int m0   = blockIdx.y * 64;
    const int n0   = blockIdx.x * 64;
    const int sr   = tid >> 2;
    const int sc   = (tid & 3) * 8;

    f32x4 acc[4] = {};

    for (int k0 = 0; k0 < K; k0 += 32) {
        __syncthreads();
        *(bf16x8*)&As[sr * 40 + sc] =
            *(const bf16x8*)(X + (size_t)(m0 + sr) * K + k0 + sc);
        *(bf16x8*)&Bs[sr * 40 + sc] =
            *(const bf16x8*)(W + (size_t)(n0 + sr) * K + k0 + sc);
        __syncthreads();

        bf16x8 a = *(bf16x8*)&As[(wv * 16 + col) * 40 + g * 8];
        #pragma unroll
        for (int jj = 0; jj < 4; ++jj) {
            bf16x8 b = *(bf16x8*)&Bs[(jj * 16 + col) * 40 + g * 8];
            acc[jj] = __builtin_amdgcn_mfma_f32_16x16x32_bf16(a, b, acc[jj], 0, 0, 0);
        }
    }

    #pragma unroll
    for (int jj = 0; jj < 4; ++jj) {
        const int cn = n0 + jj * 16 + col;
        const float bb = bias[cn];
        #pragma unroll
        for (int r = 0; r < 4; ++r) {
            const int rm = m0 + wv * 16 + g * 4 + r;
            float v = acc[jj][r] + bb;
            if (relu) v = fmaxf(v, 0.f);
            Yb[(size_t)rm * N + cn] = f32_to_bf16_rne(v);
        }
    }
}

// ---------------------------------------------------------------------------
// Fused GEMM(+bias) + residual + LayerNorm (R7-verified). Used for out-proj.
// ---------------------------------------------------------------------------
template<int K, int CR, bool DO_LN>
__global__ __launch_bounds__(256) void gemmln_kernel(
    const short* __restrict__ X, const short* __restrict__ W,
    const float* __restrict__ bias,
    float* __restrict__ hf, short* __restrict__ hb,
    const float* __restrict__ gw, const float* __restrict__ bw)
{
    constexpr int ST  = K + 8;
    constexpr int NCH = 128 / CR;
    constexpr int NF  = CR / 32;
    __shared__ short As[32 * ST];
    __shared__ short Ws[CR * ST];
    __shared__ float P[32 * 130];

    const int tid  = threadIdx.x;
    const int lane = tid & 63;
    const int wv   = tid >> 6;
    const int col  = lane & 15;
    const int g    = lane >> 4;
    const int m0   = blockIdx.x * 32;
    const int mst  = (wv & 1) * 16;
    const int cb   = (wv >> 1) * (CR / 2);

    for (int i = tid; i < 32 * (K / 8); i += 256) {
        const int r = i / (K / 8), c = (i % (K / 8)) * 8;
        *(bf16x8*)&As[r * ST + c] = *(const bf16x8*)(X + (size_t)(m0 + r) * K + c);
    }

    f32x4 ya[NCH][NF] = {};
    #pragma unroll
    for (int ch = 0; ch < NCH; ++ch) {
        for (int i = tid; i < CR * (K / 8); i += 256) {
            const int r = i / (K / 8), c = (i % (K / 8)) * 8;
            *(bf16x8*)&Ws[r * ST + c] =
                *(const bf16x8*)(W + (size_t)(ch * CR + r) * K + c);
        }
        __syncthreads();
        #pragma unroll
        for (int k0 = 0; k0 < K; k0 += 32) {
            bf16x8 a = *(bf16x8*)&As[(mst + col) * ST + k0 + g * 8];
            #pragma unroll
            for (int f = 0; f < NF; ++f) {
                bf16x8 b = *(bf16x8*)&Ws[(cb + f * 16 + col) * ST + k0 + g * 8];
                ya[ch][f] = __builtin_amdgcn_mfma_f32_16x16x32_bf16(a, b, ya[ch][f], 0, 0, 0);
            }
        }
        __syncthreads();
    }

    #pragma unroll
    for (int ch = 0; ch < NCH; ++ch)
        #pragma unroll
        for (int f = 0; f < NF; ++f) {
            const int cn = ch * CR + cb + f * 16 + col;
            const float bb = bias[cn];
            #pragma unroll
            for (int r = 0; r < 4; ++r)
                P[(mst + g * 4 + r) * 130 + cn] = ya[ch][f][r] + bb;
        }
    __syncthreads();

    #pragma unroll
    for (int rr = 0; rr < 8; ++rr) {
        const int row = wv * 8 + rr;
        const size_t t = m0 + row;
        float2 pv = *(float2*)&P[row * 130 + 2 * lane];
        if (DO_LN) {
            float2 hv = ((const float2*)(hf + t * Hh))[lane];
            float a0 = hv.x + pv.x, a1 = hv.y + pv.y;
            float sum = a0 + a1;
            #pragma unroll
            for (int off = 32; off > 0; off >>= 1) sum += __shfl_xor(sum, off);
            const float mean = sum * (1.f / 128.f);
            const float d0 = a0 - mean, d1 = a1 - mean;
            float vs = d0 * d0 + d1 * d1;
            #pragma unroll
            for (int off = 32; off > 0; off >>= 1) vs += __shfl_xor(vs, off);
            const float rstd = rsqrtf(vs * (1.f / 128.f) + 1e-5f);
            float2 gv = ((const float2*)gw)[lane];
            float2 bv = ((const float2*)bw)[lane];
            float2 r = { d0 * rstd * gv.x + bv.x, d1 * rstd * gv.y + bv.y };
            ((float2*)(hf + t * Hh))[lane] = r;
            *(unsigned*)&hb[t * Hh + lane * 2] = pack2_bf16(r.x, r.y);
        } else {
            ((float2*)(hf + t * Hh))[lane] = pv;
            *(unsigned*)&hb[t * Hh + lane * 2] = pack2_bf16(pv.x, pv.y);
        }
    }
}

// ---------------------------------------------------------------------------
// NEW: two-stage fused MLP. y = (relu(X@W1^T+b1))@W2^T+b2 [+ residual+LN].
// Block = 32 rows. u kept in LDS as bf16 (same rounding as the old global
// round-trip). W chunk buffer Ws reused sequentially with barriers on both
// sides of every restage; all other LDS arrays separate (no aliasing).
// FFN:    K=128, MID=256, CR1=64, CR2=32, DO_LN=1  (59.6 KB LDS)
// Fusion: K=256, MID=128, CR1=32, CR2=64, DO_LN=0  (59.6 KB LDS)
// ---------------------------------------------------------------------------
template<int K, int MID, int CR1, int CR2, bool DO_LN>
__global__ __launch_bounds__(256) void mlp2_kernel(
    const short* __restrict__ X,
    const short* __restrict__ W1, const float* __restrict__ b1,
    const short* __restrict__ W2, const float* __restrict__ b2,
    float* __restrict__ hf, short* __restrict__ hb,
    const float* __restrict__ gw, const float* __restrict__ bw)
{
    constexpr int STA = K + 8;
    constexpr int STU = MID + 8;
    constexpr int WS1 = CR1 * STA;
    constexpr int WS2 = CR2 * STU;
    constexpr int WSZ = (WS1 > WS2) ? WS1 : WS2;
    __shared__ short As[32 * STA];
    __shared__ short Ws[WSZ];
    __shared__ short U[32 * STU];
    __shared__ float P[32 * 130];

    const int tid  = threadIdx.x;
    const int lane = tid & 63;
    const int wv   = tid >> 6;
    const int col  = lane & 15;
    const int g    = lane >> 4;
    const int m0   = blockIdx.x * 32;
    const int mst  = (wv & 1) * 16;

    // stage A rows (32 x K)
    for (int i = tid; i < 32 * (K / 8); i += 256) {
        const int r = i / (K / 8), c = (i % (K / 8)) * 8;
        *(bf16x8*)&As[r * STA + c] = *(const bf16x8*)(X + (size_t)(m0 + r) * K + c);
    }

    // ---- stage 1: u = relu(X@W1^T + b1), u in LDS ----
    constexpr int NCH1 = MID / CR1;
    constexpr int NF1  = CR1 / 32;
    const int cb1 = (wv >> 1) * (CR1 / 2);
    #pragma unroll
    for (int ch = 0; ch < NCH1; ++ch) {
        for (int i = tid; i < CR1 * (K / 8); i += 256) {
            const int r = i / (K / 8), c = (i % (K / 8)) * 8;
            *(bf16x8*)&Ws[r * STA + c] =
                *(const bf16x8*)(W1 + (size_t)(ch * CR1 + r) * K + c);
        }
        __syncthreads();                    // As + Ws staged; prev readers done
        f32x4 ya[NF1] = {};
        #pragma unroll
        for (int k0 = 0; k0 < K; k0 += 32) {
            bf16x8 a = *(bf16x8*)&As[(mst + col) * STA + k0 + g * 8];
            #pragma unroll
            for (int f = 0; f < NF1; ++f) {
                bf16x8 b = *(bf16x8*)&Ws[(cb1 + f * 16 + col) * STA + k0 + g * 8];
                ya[f] = __builtin_amdgcn_mfma_f32_16x16x32_bf16(a, b, ya[f], 0, 0, 0);
            }
        }
        #pragma unroll
        for (int f = 0; f < NF1; ++f) {
            const int cn = ch * CR1 + cb1 + f * 16 + col;
            const float bb = b1[cn];
            #pragma unroll
            for (int r = 0; r < 4; ++r)
                U[(mst + g * 4 + r) * STU + cn] =
                    f32_to_bf16_rne(fmaxf(ya[f][r] + bb, 0.f));
        }
        __syncthreads();                    // Ws reads + U writes done
    }

    // ---- stage 2: y = u@W2^T + b2 ----
    constexpr int NCH2 = 128 / CR2;
    constexpr int NF2  = CR2 / 32;
    const int cb2 = (wv >> 1) * (CR2 / 2);
    f32x4 yb[NCH2][NF2] = {};
    #pragma unroll
    for (int ch = 0; ch < NCH2; ++ch) {
        for (int i = tid; i < CR2 * (MID / 8); i += 256) {
            const int r = i / (MID / 8), c = (i % (MID / 8)) * 8;
            *(bf16x8*)&Ws[r * STU + c] =
                *(const bf16x8*)(W2 + (size_t)(ch * CR2 + r) * MID + c);
        }
        __syncthreads();
        #pragma unroll
        for (int k0 = 0; k0 < MID; k0 += 32) {
            bf16x8 a = *(bf16x8*)&U[(mst + col) * STU + k0 + g * 8];
            #pragma unroll
            for (int f = 0; f < NF2; ++f) {
                bf16x8 b = *(bf16x8*)&Ws[(cb2 + f * 16 + col) * STU + k0 + g * 8];
                yb[ch][f] = __builtin_amdgcn_mfma_f32_16x16x32_bf16(a, b, yb[ch][f], 0, 0, 0);
            }
        }
        __syncthreads();
    }

    // ---- P scatter + epilogue (verified gemmln pattern) ----
    #pragma unroll
    for (int ch = 0; ch < NCH2; ++ch)
        #pragma unroll
        for (int f = 0; f < NF2; ++f) {
            const int cn = ch * CR2 + cb2 + f * 16 + col;
            const float bb = b2[cn];
            #pragma unroll
            for (int r = 0; r < 4; ++r)
                P[(mst + g * 4 + r) * 130 + cn] = yb[ch][f][r] + bb;
        }
    __syncthreads();

    #pragma unroll
    for (int rr = 0; rr < 8; ++rr) {
        const int row = wv * 8 + rr;
        const size_t t = m0 + row;
        float2 pv = *(float2*)&P[row * 130 + 2 * lane];
        if (DO_LN) {
            float2 hv = ((const float2*)(hf + t * Hh))[lane];
            float a0 = hv.x + pv.x, a1 = hv.y + pv.y;
            float sum = a0 + a1;
            #pragma unroll
            for (int off = 32; off > 0; off >>= 1) sum += __shfl_xor(sum, off);
            const float mean = sum * (1.f / 128.f);
            const float d0 = a0 - mean, d1 = a1 - mean;
            float vs = d0 * d0 + d1 * d1;
            #pragma unroll
            for (int off = 32; off > 0; off >>= 1) vs += __shfl_xor(vs, off);
            const float rstd = rsqrtf(vs * (1.f / 128.f) + 1e-5f);
            float2 gv = ((const float2*)gw)[lane];
            float2 bv = ((const float2*)bw)[lane];
            float2 r = { d0 * rstd * gv.x + bv.x, d1 * rstd * gv.y + bv.y };
            ((float2*)(hf + t * Hh))[lane] = r;
            *(unsigned*)&hb[t * Hh + lane * 2] = pack2_bf16(r.x, r.y);
        } else {
            ((float2*)(hf + t * Hh))[lane] = pv;
            *(unsigned*)&hb[t * Hh + lane * 2] = pack2_bf16(pv.x, pv.y);
        }
    }
}

// ---------------------------------------------------------------------------
// Fused head (R7-verified)
// ---------------------------------------------------------------------------
__global__ __launch_bounds__(256) void head_kernel(
    const short* __restrict__ X,
    const short* __restrict__ W1b, const float* __restrict__ b1,
    const short* __restrict__ DW1b, const float* __restrict__ db1,
    const float* __restrict__ w2, const float* __restrict__ b2,
    const float* __restrict__ dw2, const float* __restrict__ db2,
    float* __restrict__ out)
{
    constexpr int K = 128, ST = K + 8;
    __shared__ short As[32 * ST];
    __shared__ short Ws[64 * ST];
    __shared__ float P[32 * 196];

    const int tid  = threadIdx.x;
    const int lane = tid & 63;
    const int wv   = tid >> 6;
    const int col  = lane & 15;
    const int g    = lane >> 4;
    const int m0   = blockIdx.x * 32;
    const int mst  = (wv & 1) * 16;
    const int cb   = (wv >> 1) * 32;

    for (int i = tid; i < 32 * (K / 8); i += 256) {
        const int r = i / (K / 8), c = (i % (K / 8)) * 8;
        *(bf16x8*)&As[r * ST + c] = *(const bf16x8*)(X + (size_t)(m0 + r) * K + c);
    }

    f32x4 ya[3][2] = {};
    #pragma unroll
    for (int ch = 0; ch < 3; ++ch) {
        for (int i = tid; i < 64 * (K / 8); i += 256) {
            const int r = i / (K / 8), c = (i % (K / 8)) * 8;
            const int rg = ch * 64 + r;
            const short* src = (rg < 128) ? (W1b + (size_t)rg * K)
                                          : (DW1b + (size_t)(rg - 128) * K);
            *(bf16x8*)&Ws[r * ST + c] = *(const bf16x8*)(src + c);
        }
        __syncthreads();
        #pragma unroll
        for (int k0 = 0; k0 < K; k0 += 32) {
            bf16x8 a = *(bf16x8*)&As[(mst + col) * ST + k0 + g * 8];
            #pragma unroll
            for (int f = 0; f < 2; ++f) {
                bf16x8 b = *(bf16x8*)&Ws[(cb + f * 16 + col) * ST + k0 + g * 8];
                ya[ch][f] = __builtin_amdgcn_mfma_f32_16x16x32_bf16(a, b, ya[ch][f], 0, 0, 0);
            }
        }
        __syncthreads();
    }

    #pragma unroll
    for (int ch = 0; ch < 3; ++ch)
        #pragma unroll
        for (int f = 0; f < 2; ++f) {
            const int cn = ch * 64 + cb + f * 16 + col;
            const float bb = (cn < 128) ? b1[cn] : db1[cn - 128];
            #pragma unroll
            for (int r = 0; r < 4; ++r)
                P[(mst + g * 4 + r) * 196 + cn] = fmaxf(ya[ch][f][r] + bb, 0.f);
        }
    __syncthreads();

    const float w20 = w2[2 * lane],       w21 = w2[2 * lane + 1];
    const float w22 = w2[128 + 2 * lane], w23 = w2[129 + 2 * lane];
    const float w24 = w2[256 + 2 * lane], w25 = w2[257 + 2 * lane];
    const float dwl = dw2[lane];
    float qacc = 0.f;
    #pragma unroll
    for (int rr = 0; rr < 8; ++rr) {
        const int row = wv * 8 + rr;
        const size_t t = m0 + row;
        const float x0 = P[row * 196 + 2 * lane];
        const float x1 = P[row * 196 + 2 * lane + 1];
        float s0 = x0 * w20 + x1 * w21;
        float s1 = x0 * w22 + x1 * w23;
        float s2 = x0 * w24 + x1 * w25;
        float d  = P[row * 196 + 128 + lane] * dwl;
        #pragma unroll
        for (int off = 32; off > 0; off >>= 1) {
            s0 += __shfl_xor(s0, off);
            s1 += __shfl_xor(s1, off);
            s2 += __shfl_xor(s2, off);
            d  += __shfl_xor(d,  off);
        }
        if (lane == 0) {
            out[t * 3 + 0] = s0 + b2[0];
            out[t * 3 + 1] = s1 + b2[1];
            out[t * 3 + 2] = s2 + b2[2];
            const float prob = 1.f / (1.f + __expf(-(d + db2[0])));
            out[24576 + t] = prob;
            qacc += prob;
        }
    }
    if (lane == 0)
        atomicAdd(&out[32768 + (m0 >> 11)], qacc * (1.f / (float)Nn));
}

// ---------------------------------------------------------------------------
// MFMA flash attention — byte-identical to R9 (verified: no-max softmax,
// ones-MFMA row sum)
// ---------------------------------------------------------------------------
constexpr int KT = 128;
constexpr int KS = 28;
constexpr int VS = 132;

__global__ __launch_bounds__(256) void attn_kernel(
    const short* __restrict__ qkv, short* __restrict__ out)
{
    __shared__ short Ks[KT * KS];
    __shared__ short Vs[DHh * VS];

    const int tid  = threadIdx.x;
    const int lane = tid & 63;
    const int wv   = tid >> 6;
    const int col  = lane & 15;
    const int g    = lane >> 4;
    const int hd   = blockIdx.y;
    const int b    = blockIdx.z;
    const int q0   = blockIdx.x * 64 + wv * 16;

    const short* base = qkv + (size_t)b * Nn * 384;

    bf16x8 qf = {};
    if (g < 2) {
        bf16x8 qraw = *(const bf16x8*)(base + (size_t)(q0 + col) * 384 + hd * DHh + g * 8);
        const float qs = 0.25f * LOG2E;
        #pragma unroll
        for (int i = 0; i < 8; ++i)
            qf[i] = f32_to_bf16_rne(bf16_to_f32(qraw[i]) * qs);
    }

    f32x4 o    = {0.f, 0.f, 0.f, 0.f};
    f32x4 lacc = {0.f, 0.f, 0.f, 0.f};
    const short one_bf16 = (short)0x3F80;
    const bf16x8 ones = { one_bf16, one_bf16, one_bf16, one_bf16,
                          one_bf16, one_bf16, one_bf16, one_bf16 };

    const int ksr = tid >> 1;
    const int ksd = (tid & 1) * 8;
    const int va  = tid >> 2;
    const int vd  = (tid & 3) * 4;

    for (int kt = 0; kt < Nn; kt += KT) {
        __syncthreads();
        {
            *(bf16x8*)&Ks[ksr * KS + ksd] =
                *(const bf16x8*)(base + (size_t)(kt + ksr) * 384 + Hh + hd * DHh + ksd);
            const short* v0 = base + (size_t)(kt + 2 * va) * 384 + 2 * Hh + hd * DHh + vd;
            bf16x4 r0 = *(const bf16x4*)v0;
            bf16x4 r1 = *(const bf16x4*)(v0 + 384);
            unsigned a0 = ((const unsigned*)&r0)[0], a1 = ((const unsigned*)&r0)[1];
            unsigned b0 = ((const unsigned*)&r1)[0], b1 = ((const unsigned*)&r1)[1];
            *(unsigned*)&Vs[(vd + 0) * VS + 2 * va] = __builtin_amdgcn_perm(b0, a0, 0x05040100);
            *(unsigned*)&Vs[(vd + 1) * VS + 2 * va] = __builtin_amdgcn_perm(b0, a0, 0x07060302);
            *(unsigned*)&Vs[(vd + 2) * VS + 2 * va] = __builtin_amdgcn_perm(b1, a1, 0x05040100);
            *(unsigned*)&Vs[(vd + 3) * VS + 2 * va] = __builtin_amdgcn_perm(b1, a1, 0x07060302);
        }
        __syncthreads();

        #pragma unroll
        for (int s = 0; s < 4; ++s) {
            bf16x8 kf0 = {}, kf1 = {};
            if (g < 2) {
                kf0 = *(bf16x8*)&Ks[(s * 32 + col) * KS + g * 8];
                kf1 = *(bf16x8*)&Ks[(s * 32 + 16 + col) * KS + g * 8];
            }
            f32x4 z = {0.f, 0.f, 0.f, 0.f};
            f32x4 sA = __builtin_amdgcn_mfma_f32_16x16x32_bf16(kf0, qf, z, 0, 0, 0);
            f32x4 sB = __builtin_amdgcn_mfma_f32_16x16x32_bf16(kf1, qf, z, 0, 0, 0);

            union { bf16x8 v; unsigned u[4]; } pf;
            pf.u[0] = pack2_bf16(__builtin_amdgcn_exp2f(sA[0]),
                                 __builtin_amdgcn_exp2f(sA[1]));
            pf.u[1] = pack2_bf16(__builtin_amdgcn_exp2f(sA[2]),
                                 __builtin_amdgcn_exp2f(sA[3]));
            pf.u[2] = pack2_bf16(__builtin_amdgcn_exp2f(sB[0]),
                                 __builtin_amdgcn_exp2f(sB[1]));
            pf.u[3] = pack2_bf16(__builtin_amdgcn_exp2f(sB[2]),
                                 __builtin_amdgcn_exp2f(sB[3]));

            bf16x8 vf;
            ((bf16x4*)&vf)[0] = *(bf16x4*)&Vs[col * VS + s * 32 + g * 4];
            ((bf16x4*)&vf)[1] = *(bf16x4*)&Vs[col * VS + s * 32 + 16 + g * 4];

            o    = __builtin_amdgcn_mfma_f32_16x16x32_bf16(pf.v, vf,   o,    0, 0, 0);
            lacc = __builtin_amdgcn_mfma_f32_16x16x32_bf16(pf.v, ones, lacc, 0, 0, 0);
        }
    }

    #pragma unroll
    for (int r = 0; r < 4; ++r) {
        const float inv = __builtin_amdgcn_rcpf(lacc[r]);
        out[(size_t)(b * Nn + q0 + g * 4 + r) * Hh + hd * DHh + col] =
            f32_to_bf16_rne(o[r] * inv);
    }
}

// ---------------------------------------------------------------------------
extern "C" void kernel_launch(void* const* d_in, const int* in_sizes, int n_in,
                              void* d_out, int out_size, void* d_ws, size_t ws_size,
                              hipStream_t stream)
{
    char* W8 = (char*)d_ws;
    float* hf   = (float*)(W8 + 0);            // 4MB  fp32 residual spine
    short* hb   = (short*)(W8 + 4194304);      // 2MB  bf16 mirror
    short* wb   = (short*)(W8 + 6291456);      // 1MB  bf16 weights
    char*  regA = W8 + 7340032;                // 6MB  xb / qkvb
    char*  regB = W8 + 13631488;               // 2MB  attno

    short* xb    = (short*)regA;               // [8192,256]
    short* qkvb  = (short*)regA;               // [8192,384]
    short* attno = (short*)regB;               // [8192,128]
    float* out   = (float*)d_out;

    const int wsz[12]  = {32768,16384,49152,16384,32768,32768,49152,16384,32768,32768,16384,8192};
    const int wsrc[12] = {1, 3, 5, 7, 9, 11, 17, 19, 21, 23, 29, 33};
    int woff[13]; woff[0] = 0;
    for (int i = 0; i < 12; ++i) woff[i + 1] = woff[i] + wsz[i];

    CvtJobs jobs;
    int acc = 0;
    for (int i = 0; i < 12; ++i) {
        jobs.src[i] = (const float*)d_in[wsrc[i]];
        jobs.dst[i] = wb + woff[i];
        jobs.off[i] = acc;
        acc += wsz[i] / 4;
    }
    jobs.src[12] = (const float*)d_in[0];
    jobs.dst[12] = xb;
    jobs.off[12] = acc;
    acc += (MTOK * Cc) / 4;
    jobs.off[13] = acc;
    jobs.qzero = out + 32768;

    hipLaunchKernelGGL(cvt_kernel, dim3((acc + 255) / 256), dim3(256), 0, stream, jobs);

    // feature fusion: h = relu(x@fw1^T+b1)@fw2^T+b2  (one fused dispatch)
    hipLaunchKernelGGL((mlp2_kernel<256, 128, 32, 64, false>), dim3(MTOK / 32), dim3(256), 0,
                       stream, xb, wb + woff[0], (const float*)d_in[2],
                       wb + woff[1], (const float*)d_in[4], hf, hb, nullptr, nullptr);

    for (int l = 0; l < 2; ++l) {
        const int ib = 5 + l * 12;
        const int wbase = 2 + l * 4;
        hipLaunchKernelGGL(gemm_bf16_kernel, dim3(384 / 64, MTOK / 64), dim3(256), 0, stream,
                           hb, wb + woff[wbase + 0], (const float*)d_in[ib + 1], qkvb,
                           MTOK, 3 * Hh, Hh, 0);
        hipLaunchKernelGGL(attn_kernel, dim3(Nn / 64, NHh, Bb), dim3(256), 0, stream,
                           qkvb, attno);
        hipLaunchKernelGGL((gemmln_kernel<128, 64, true>), dim3(MTOK / 32), dim3(256), 0, stream,
                           attno, wb + woff[wbase + 1], (const float*)d_in[ib + 3],
                           hf, hb, (const float*)d_in[ib + 8], (const float*)d_in[ib + 9]);
        // fused FFN: h = LN(h + relu(h@f1^T+b1)@f2^T+b2)
        hipLaunchKernelGGL((mlp2_kernel<128, 256, 64, 32, true>), dim3(MTOK / 32), dim3(256), 0,
                           stream, hb, wb + woff[wbase + 2], (const float*)d_in[ib + 5],
                           wb + woff[wbase + 3], (const float*)d_in[ib + 7],
                           hf, hb, (const float*)d_in[ib + 10], (const float*)d_in[ib + 11]);
    }

    hipLaunchKernelGGL(head_kernel, dim3(MTOK / 32), dim3(256), 0, stream,
                       hb, wb + woff[10], (const float*)d_in[30],
                       wb + woff[11], (const float*)d_in[34],
                       (const float*)d_in[31], (const float*)d_in[32],
                       (const float*)d_in[35], (const float*)d_in[36], out);
}